// Round 3
// baseline (18356.947 us; speedup 1.0000x reference)
//
#include <hip/hip_runtime.h>

// VQ-VAE fwd on MI355X, fp32, scalar-weight (SMEM) direct conv/deconv.
//  - deconv3 (1.1 TFLOP) folded into the 1x1 output conv -> 8.6 GF fused kernel.
//  - lane = 1 output point, Q oc in registers; weights wave-uniform
//    (repacked [ic][tap][oc]) -> s_load, no LDS traffic for weights.
//  - per-batch pipeline: peak workspace ~227 MB (was 403 MB; suspected ws
//    overrun caused the round-2 GPU memory fault).
//  - all global stores scalar dwords (d_out+1 is never 16B aligned).

// ---------------------------------------------------------------------------
// Repack weights to wT[(ic*64 + tap)*OC + oc].
// TR=false: src is conv layout (OC,IC,4,4,4). TR=true: deconv layout (IC,OC,4,4,4).
template<int IC, int OC, bool TR>
__global__ __launch_bounds__(256)
void repack_w(const float* __restrict__ src, float* __restrict__ dst)
{
    int idx = blockIdx.x * 256 + threadIdx.x;
    if (idx >= IC * OC * 64) return;
    int oc  = idx % OC;
    int rem = idx / OC;
    int tap = rem % 64;
    int ic  = rem / 64;
    float v = TR ? src[(ic * OC + oc) * 64 + tap]
                 : src[(oc * IC + ic) * 64 + tap];
    dst[idx] = v;
}

// ---------------------------------------------------------------------------
// conv k=4 s=2 p=1 (one batch). Block: 4x8x8 out spatial, Q oc. Thread: 1 point.
// Input tile 10x18x18 per ic, parity-deinterleaved: [8 parity][5*9*9] (stride 9).
template<int IC, int OC, int IND, bool RELU, int ICC, int Q>
__global__ __launch_bounds__(256)
void conv_sw(const float* __restrict__ in, const float* __restrict__ wT,
             const float* __restrict__ bias, float* __restrict__ out)
{
    constexpr int OUTD = IND / 2;
    constexpr int NTW = OUTD / 8, NTH = OUTD / 8;
    __shared__ float sIn[ICC][8][405];

    const int t = threadIdx.x;
    const int bx = blockIdx.x;
    const int twi = bx % NTW;
    const int thi = (bx / NTW) % NTH;
    const int tdi = bx / (NTW * NTH);
    const int ocBase = blockIdx.y * Q;

    const int d = t >> 6;          // 0..3
    const int h = (t >> 3) & 7;    // 0..7
    const int w = t & 7;           // 0..7

    float acc[Q];
    #pragma unroll
    for (int j = 0; j < Q; ++j) acc[j] = bias[ocBase + j];

    const int id0 = 2 * (tdi * 4) - 1;
    const int ih0 = 2 * (thi * 8) - 1;
    const int iw0 = 2 * (twi * 8) - 1;

    #pragma unroll 1
    for (int ic0 = 0; ic0 < IC; ic0 += ICC) {
        __syncthreads();
        for (int p = t; p < ICC * 3240; p += 256) {
            int icc = p / 3240;
            int r   = p - icc * 3240;
            int li  = r / 324;
            int r2  = r - li * 324;
            int lh  = r2 / 18;
            int lw  = r2 - lh * 18;
            int gd = id0 + li, gh = ih0 + lh, gw = iw0 + lw;
            float v = 0.0f;
            if ((unsigned)gd < (unsigned)IND && (unsigned)gh < (unsigned)IND &&
                (unsigned)gw < (unsigned)IND)
                v = in[((ic0 + icc) * IND + gd) * IND * IND + gh * IND + gw];
            sIn[icc][((li & 1) << 2) | ((lh & 1) << 1) | (lw & 1)]
               [(li >> 1) * 81 + (lh >> 1) * 9 + (lw >> 1)] = v;
        }
        __syncthreads();
        #pragma unroll 1
        for (int icc = 0; icc < ICC; ++icc) {
            const int ic = ic0 + icc;
            #pragma unroll 1
            for (int kd = 0; kd < 4; ++kd) {
                #pragma unroll
                for (int kh = 0; kh < 4; ++kh)
                #pragma unroll
                for (int kw = 0; kw < 4; ++kw) {
                    const float iv = sIn[icc][((kd & 1) << 2) | ((kh & 1) << 1) | (kw & 1)]
                        [(d + (kd >> 1)) * 81 + (h + (kh >> 1)) * 9 + (w + (kw >> 1))];
                    const float* __restrict__ wr =
                        wT + (ic * 64 + (kd * 16 + kh * 4 + kw)) * OC + ocBase;
                    #pragma unroll
                    for (int j = 0; j < Q; ++j) acc[j] = fmaf(iv, wr[j], acc[j]);
                }
            }
        }
    }

    const int od = tdi * 4 + d;
    const int oh = thi * 8 + h;
    const int ow = twi * 8 + w;
    #pragma unroll
    for (int j = 0; j < Q; ++j) {
        float v = acc[j];
        if (RELU) v = fmaxf(v, 0.0f);
        out[((ocBase + j) * OUTD + od) * OUTD * OUTD + oh * OUTD + ow] = v;
    }
}

// ---------------------------------------------------------------------------
// ConvTranspose3d k=4 s=2 p=1 (one batch). out[o] += in[i]*w[k], o = 2i+k-1.
// Block: 8x8x8 out tile, Q oc. Wave q: (h,w)-parity (q>>1,q&1) (SGPR-hoisted);
// lane: (d2,h2,w2); thread covers d-parity pd in {0,1}: acc[2][Q].
template<int IC, int OC, int IND, bool RELU, int ICC, int Q>
__global__ __launch_bounds__(256)
void deconv_sw(const float* __restrict__ in, const float* __restrict__ dwT,
               const float* __restrict__ bias, float* __restrict__ out)
{
    constexpr int OUTD = IND * 2;
    constexpr int NT = OUTD / 8;
    __shared__ float sIn[ICC][216];      // 6x6x6 per ic

    const int t = threadIdx.x;
    const int bx = blockIdx.x;
    const int twi = bx % NT;
    const int thi = (bx / NT) % NT;
    const int tdi = bx / (NT * NT);
    const int ocBase = blockIdx.y * Q;

    const int qv = __builtin_amdgcn_readfirstlane(t >> 6);  // wave id, uniform
    const int ph = qv >> 1, pw = qv & 1;
    const int l  = t & 63;
    const int d2 = l >> 4;           // 0..3
    const int h2 = (l >> 2) & 3;     // 0..3
    const int w2 = l & 3;            // 0..3

    float acc[2][Q];
    #pragma unroll
    for (int j = 0; j < Q; ++j) {
        float bv = bias[ocBase + j];
        acc[0][j] = bv; acc[1][j] = bv;
    }

    const int ibd = 4 * tdi - 1;
    const int ibh = 4 * thi - 1;
    const int ibw = 4 * twi - 1;

    #pragma unroll 1
    for (int ic0 = 0; ic0 < IC; ic0 += ICC) {
        __syncthreads();
        for (int p = t; p < ICC * 216; p += 256) {
            int icc = p / 216;
            int r   = p - icc * 216;
            int li  = r / 36;
            int r2  = r - li * 36;
            int lh  = r2 / 6;
            int lw  = r2 - lh * 6;
            int gd = ibd + li, gh = ibh + lh, gw = ibw + lw;
            float v = 0.0f;
            if ((unsigned)gd < (unsigned)IND && (unsigned)gh < (unsigned)IND &&
                (unsigned)gw < (unsigned)IND)
                v = in[((ic0 + icc) * IND + gd) * IND * IND + gh * IND + gw];
            sIn[icc][r] = v;
        }
        __syncthreads();
        #pragma unroll 1
        for (int icc = 0; icc < ICC; ++icc) {
            const int ic = ic0 + icc;
            #pragma unroll
            for (int pd = 0; pd < 2; ++pd)
            #pragma unroll
            for (int sdl = 0; sdl < 2; ++sdl)
            #pragma unroll
            for (int shl = 0; shl < 2; ++shl)
            #pragma unroll
            for (int swl = 0; swl < 2; ++swl) {
                const int td_ = (sdl ? 1 : 3) - pd;     // uniform
                const int th_ = (shl ? 1 : 3) - ph;
                const int tw_ = (swl ? 1 : 3) - pw;
                const int tap = td_ * 16 + th_ * 4 + tw_;
                const float iv = sIn[icc][(d2 + pd + sdl) * 36 + (h2 + ph + shl) * 6
                                          + (w2 + pw + swl)];
                const float* __restrict__ wr = dwT + (ic * 64 + tap) * OC + ocBase;
                #pragma unroll
                for (int j = 0; j < Q; ++j) acc[pd][j] = fmaf(iv, wr[j], acc[pd][j]);
            }
        }
    }

    #pragma unroll
    for (int pd = 0; pd < 2; ++pd) {
        const int od = tdi * 8 + 2 * d2 + pd;
        const int oh = thi * 8 + 2 * h2 + ph;
        const int ow = twi * 8 + 2 * w2 + pw;
        #pragma unroll
        for (int j = 0; j < Q; ++j) {
            float v = acc[pd][j];
            if (RELU) v = fmaxf(v, 0.0f);
            out[((ocBase + j) * OUTD + od) * OUTD * OUTD + oh * OUTD + ow] = v;
        }
    }
}

// ---------------------------------------------------------------------------
// Fused (deconv3 . conv1x1), one batch: dwe[ic*64+tap], scalar be.
// Thread: 4x4x4 output block; inputs -> registers; 512 FMAs/ic; SCALAR stores
// (out = d_out+1+..., never 16B-aligned).
__global__ __launch_bounds__(256)
void deconv_final_sw(const float* __restrict__ in, const float* __restrict__ dwe,
                     const float* __restrict__ beP, float* __restrict__ out)
{
    constexpr int IC = 128, IND = 64, OUTD = 128, ICC = 2;
    __shared__ float sIn[ICC][3240];     // 10 x 18 x 18, row stride 18

    const int t = threadIdx.x;
    const int bx = blockIdx.x;           // 8 d-tiles x 4 h x 4 w
    const int bw = bx & 3;
    const int bh = (bx >> 2) & 3;
    const int bd = bx >> 4;

    const int td_ = t >> 6;              // 0..3
    const int th_ = (t >> 3) & 7;        // 0..7
    const int tw_ = t & 7;               // 0..7

    const int gd0 = 8 * bd - 1;
    const int gh0 = 16 * bh - 1;
    const int gw0 = 16 * bw - 1;

    float acc[4][4][4];
    #pragma unroll
    for (int a = 0; a < 4; ++a)
        #pragma unroll
        for (int bq = 0; bq < 4; ++bq)
            #pragma unroll
            for (int c = 0; c < 4; ++c) acc[a][bq][c] = 0.0f;

    // (il, k, ol) pair table for one dim: ol = 2*il + k - 3
    constexpr int PI[8] = {0,1,1,1,2,2,2,3};
    constexpr int PK[8] = {3,1,2,3,0,1,2,0};
    constexpr int PO[8] = {0,0,1,2,1,2,3,3};

    #pragma unroll 1
    for (int ic0 = 0; ic0 < IC; ic0 += ICC) {
        __syncthreads();
        for (int p = t; p < ICC * 3240; p += 256) {
            int icc = p / 3240;
            int r   = p - icc * 3240;
            int li  = r / 324;
            int r2  = r - li * 324;
            int lh  = r2 / 18;
            int lw  = r2 - lh * 18;
            int gd = gd0 + li, gh = gh0 + lh, gw = gw0 + lw;
            float v = 0.0f;
            if ((unsigned)gd < (unsigned)IND && (unsigned)gh < (unsigned)IND &&
                (unsigned)gw < (unsigned)IND)
                v = in[((ic0 + icc) * IND + gd) * IND * IND + gh * IND + gw];
            sIn[icc][r] = v;
        }
        __syncthreads();
        #pragma unroll 1
        for (int icc = 0; icc < ICC; ++icc) {
            const int ic = ic0 + icc;
            const float* __restrict__ wv = dwe + ic * 64;   // uniform -> s_load
            float riv[4][4][4];
            #pragma unroll
            for (int id = 0; id < 4; ++id)
                #pragma unroll
                for (int ih = 0; ih < 4; ++ih) {
                    const int off = (2 * td_ + id) * 324 + (2 * th_ + ih) * 18 + 2 * tw_;
                    const float2 r01 = *(const float2*)&sIn[icc][off];
                    const float2 r23 = *(const float2*)&sIn[icc][off + 2];
                    riv[id][ih][0] = r01.x; riv[id][ih][1] = r01.y;
                    riv[id][ih][2] = r23.x; riv[id][ih][3] = r23.y;
                }
            #pragma unroll
            for (int a = 0; a < 8; ++a)
                #pragma unroll
                for (int bq = 0; bq < 8; ++bq)
                    #pragma unroll
                    for (int c = 0; c < 8; ++c)
                        acc[PO[a]][PO[bq]][PO[c]] =
                            fmaf(riv[PI[a]][PI[bq]][PI[c]],
                                 wv[PK[a] * 16 + PK[bq] * 4 + PK[c]],
                                 acc[PO[a]][PO[bq]][PO[c]]);
        }
    }

    const float be = *beP;
    #pragma unroll
    for (int a = 0; a < 4; ++a)
        #pragma unroll
        for (int bq = 0; bq < 4; ++bq) {
            const int od = 16 * bd + 4 * td_ + a;
            const int oh = 32 * bh + 4 * th_ + bq;
            const int ow = 32 * bw + 4 * tw_;
            float* orow = &out[(od * OUTD + oh) * OUTD + ow];
            orow[0] = acc[a][bq][0] + be;
            orow[1] = acc[a][bq][1] + be;
            orow[2] = acc[a][bq][2] + be;
            orow[3] = acc[a][bq][3] + be;
        }
}

// ---------------------------------------------------------------------------
__global__ void esq_kernel(const float* __restrict__ emb, float* __restrict__ eSq)
{
    int k = blockIdx.x * 256 + threadIdx.x;
    if (k < 512) {
        float s = 0.0f;
        #pragma unroll
        for (int e = 0; e < 64; ++e) { float v = emb[k * 64 + e]; s += v * v; }
        eSq[k] = s;
    }
}

// dwe[ic*64+tap] = sum_c dw3[ic][c][tap] * wo[c];  be = bo + sum_c wo[c]*db3[c]
__global__ void fold_kernel(const float* __restrict__ dw3, const float* __restrict__ wo,
                            const float* __restrict__ db3, const float* __restrict__ bo,
                            float* __restrict__ dwe, float* __restrict__ beP)
{
    int idx = blockIdx.x * 256 + threadIdx.x;   // 8192 = 128 ic x 64 tap
    int ic = idx >> 6, tap = idx & 63;
    float s = 0.0f;
    for (int c = 0; c < 128; ++c) s += dw3[(ic * 128 + c) * 64 + tap] * wo[c];
    dwe[idx] = s;
    if (idx == 0) {
        float bb = bo[0];
        for (int c = 0; c < 128; ++c) bb += wo[c] * db3[c];
        *beP = bb;
    }
}

__global__ void zero_kernel(float* __restrict__ p)
{
    if (threadIdx.x == 0) p[0] = 0.0f;
}

// One batch: 16384 code-vectors. One lane per vector; k-range split across the
// 4 waves. dist mimics reference rounding: (||f||^2 + ||e_k||^2) - 2 f.e_k,
// first-min tie-break (matches jnp.argmin semantics incl. its quantization).
__global__ __launch_bounds__(256)
void vq_kernel(const float* __restrict__ h3, const float* __restrict__ emb,
               const float* __restrict__ eSq, float* __restrict__ q,
               float* __restrict__ lossAcc)
{
    __shared__ float sDist[4][64];
    __shared__ int   sIdx[4][64];
    const int t = threadIdx.x;
    const int vec = blockIdx.x * 64 + (t & 63);   // < 16384
    const int kq = t >> 6;
    const int cg = vec & 3;
    const int spat = vec >> 2;                    // 0..4095
    const int base = (cg * 64) * 4096 + spat;

    float v[64];
    #pragma unroll
    for (int e = 0; e < 64; ++e) v[e] = h3[base + e * 4096];

    float fSq = 0.0f;
    #pragma unroll
    for (int e = 0; e < 64; ++e) fSq += v[e] * v[e];

    float best = 1e30f; int bidx = 0;
    const int k0 = __builtin_amdgcn_readfirstlane(kq) * 128;
    for (int kk = 0; kk < 128; ++kk) {
        const int k = k0 + kk;
        const float* er = emb + k * 64;
        float d0 = 0, d1 = 0, d2 = 0, d3 = 0;
        #pragma unroll
        for (int e = 0; e < 64; e += 4) {
            d0 += v[e]     * er[e];
            d1 += v[e + 1] * er[e + 1];
            d2 += v[e + 2] * er[e + 2];
            d3 += v[e + 3] * er[e + 3];
        }
        const float s1 = fSq + eSq[k];
        const float dist = s1 - 2.0f * ((d0 + d1) + (d2 + d3));
        if (dist < best) { best = dist; bidx = k; }
    }
    sDist[kq][t & 63] = best;
    sIdx[kq][t & 63]  = bidx;
    __syncthreads();
    if (t < 64) {
        float bd = sDist[0][t]; int bi = sIdx[0][t];
        #pragma unroll
        for (int j = 1; j < 4; ++j) {
            float d = sDist[j][t]; int i2 = sIdx[j][t];
            if (d < bd || (d == bd && i2 < bi)) { bd = d; bi = i2; }
        }
        const float* er = emb + bi * 64;
        float ls = 0.0f;
        #pragma unroll
        for (int e = 0; e < 64; ++e) {
            float qe = er[e];
            q[base + e * 4096] = qe;
            float df = qe - v[e];
            ls += df * df;
        }
        #pragma unroll
        for (int off = 32; off > 0; off >>= 1) ls += __shfl_down(ls, off);
        if (t == 0) atomicAdd(lossAcc, ls);
    }
}

__global__ void loss_final(const float* __restrict__ lossAcc, float* __restrict__ out)
{
    // loss = (1 + 0.25) * mean((q-h)^2), mean over 2*16384*64 elements
    out[0] = 1.25f * lossAcc[0] / 2097152.0f;
}

// ---------------------------------------------------------------------------
extern "C" void kernel_launch(void* const* d_in, const int* in_sizes, int n_in,
                              void* d_out, int out_size, void* d_ws, size_t ws_size,
                              hipStream_t stream)
{
    (void)in_sizes; (void)n_in; (void)out_size; (void)ws_size;
    const float* x   = (const float*)d_in[0];
    const float* w1  = (const float*)d_in[1];
    const float* b1  = (const float*)d_in[2];
    const float* w2  = (const float*)d_in[3];
    const float* b2  = (const float*)d_in[4];
    const float* w3  = (const float*)d_in[5];
    const float* b3  = (const float*)d_in[6];
    const float* dw1 = (const float*)d_in[7];
    const float* db1 = (const float*)d_in[8];
    const float* dw2 = (const float*)d_in[9];
    const float* db2 = (const float*)d_in[10];
    const float* dw3 = (const float*)d_in[11];
    const float* db3 = (const float*)d_in[12];
    const float* wo  = (const float*)d_in[13];
    const float* bo  = (const float*)d_in[14];
    const float* emb = (const float*)d_in[15];

    // Workspace layout (floats), peak ~56.6M floats = 227 MB:
    float* ws   = (float*)d_ws;
    float* A    = ws;                    // 33,554,432  h1 / r2 (one batch)
    float* Bb   = A + 33554432;          //  8,388,608  h2 / r1
    float* C    = Bb + 8388608;          //  1,048,576  h3
    float* D    = C + 1048576;           //  1,048,576  q
    float* wT1  = D + 1048576;           //      8,192
    float* wT2  = wT1 + 8192;            //  2,097,152
    float* wT3  = wT2 + 2097152;         //  4,194,304
    float* dwT1 = wT3 + 4194304;         //  4,194,304
    float* dwT2 = dwT1 + 4194304;        //  2,097,152
    float* dwe  = dwT2 + 2097152;        //      8,192
    float* eSq  = dwe + 8192;            //        512
    float* lossAcc = eSq + 512;          //          1
    float* beP  = lossAcc + 1;           //          1

    float* outLoss = (float*)d_out;
    float* outR    = (float*)d_out + 1;

    zero_kernel<<<dim3(1), 64, 0, stream>>>(lossAcc);

    // weight prep (once; reused by both batches)
    repack_w<1,   128, false><<<dim3(32),    256, 0, stream>>>(w1,  wT1);
    repack_w<128, 256, false><<<dim3(8192),  256, 0, stream>>>(w2,  wT2);
    repack_w<256, 256, false><<<dim3(16384), 256, 0, stream>>>(w3,  wT3);
    repack_w<256, 256, true ><<<dim3(16384), 256, 0, stream>>>(dw1, dwT1);
    repack_w<256, 128, true ><<<dim3(8192),  256, 0, stream>>>(dw2, dwT2);
    fold_kernel<<<dim3(32), 256, 0, stream>>>(dw3, wo, db3, bo, dwe, beP);
    esq_kernel<<<dim3(2), 256, 0, stream>>>(emb, eSq);

    for (int b = 0; b < 2; ++b) {
        const float* xb = x + (size_t)b * 2097152;       // [1,128,128,128]
        float* rb = outR + (size_t)b * 2097152;          // [1,128,128,128]

        conv_sw<1,   128, 128, true,  1, 64><<<dim3(1024, 2), 256, 0, stream>>>(xb, wT1, b1, A);
        conv_sw<128, 256, 64,  true,  2, 64><<<dim3(128,  4), 256, 0, stream>>>(A,  wT2, b2, Bb);
        conv_sw<256, 256, 32,  false, 2, 16><<<dim3(16,  16), 256, 0, stream>>>(Bb, wT3, b3, C);

        vq_kernel<<<dim3(256), 256, 0, stream>>>(C, emb, eSq, D, lossAcc);

        deconv_sw<256, 256, 16, true, 8, 32><<<dim3(64,  8), 256, 0, stream>>>(D,  dwT1, db1, Bb);
        deconv_sw<256, 128, 32, true, 8, 32><<<dim3(512, 4), 256, 0, stream>>>(Bb, dwT2, db2, A);
        deconv_final_sw<<<dim3(128), 256, 0, stream>>>(A, dwe, beP, rb);
    }

    loss_final<<<dim3(1), 1, 0, stream>>>(lossAcc, outLoss);
}

// Round 4
// 14364.830 us; speedup vs baseline: 1.2779x; 1.2779x over previous
//
#include <hip/hip_runtime.h>

// VQ-VAE fwd on MI355X, fp32, scalar-weight (SMEM) direct conv/deconv.
//  - deconv3 (1.1 TFLOP) folded into the 1x1 output conv -> 8.6 GF fused kernel.
//  - lane = 1 output point, Q oc in registers; weights wave-uniform
//    (repacked [ic][tap][oc]) -> s_load, no LDS traffic for weights.
//  - R4: occupancy fixes. conv2: Q=32, 8 oc-blocks (512->1024 blocks).
//    conv3/deconv1: split-K=2 over IC + float4 reduce (1->2, 2->4 blocks/CU).
//    R3 measured conv2: occ 24.4% (grid-limited), VALUBusy 43.5%.

// ---------------------------------------------------------------------------
// Repack weights to wT[(ic*64 + tap)*OC + oc].
// TR=false: src is conv layout (OC,IC,4,4,4). TR=true: deconv layout (IC,OC,4,4,4).
template<int IC, int OC, bool TR>
__global__ __launch_bounds__(256)
void repack_w(const float* __restrict__ src, float* __restrict__ dst)
{
    int idx = blockIdx.x * 256 + threadIdx.x;
    if (idx >= IC * OC * 64) return;
    int oc  = idx % OC;
    int rem = idx / OC;
    int tap = rem % 64;
    int ic  = rem / 64;
    float v = TR ? src[(ic * OC + oc) * 64 + tap]
                 : src[(oc * IC + ic) * 64 + tap];
    dst[idx] = v;
}

// ---------------------------------------------------------------------------
// conv k=4 s=2 p=1 (one batch). Block: 4x8x8 out spatial, Q oc. Thread: 1 point.
// Input tile 10x18x18 per ic, parity-deinterleaved: [8 parity][5*9*9] (stride 9).
// KS>1: blockIdx.z selects an IC/KS chunk; raw partials to out + z*OC*OUTD^3
// (bias+ReLU applied in reduce2_bias).
template<int IC, int OC, int IND, bool RELU, int ICC, int Q, int KS>
__global__ __launch_bounds__(256)
void conv_sw(const float* __restrict__ in, const float* __restrict__ wT,
             const float* __restrict__ bias, float* __restrict__ out)
{
    constexpr int OUTD = IND / 2;
    constexpr int NTW = OUTD / 8, NTH = OUTD / 8;
    constexpr int ICB = IC / KS;
    __shared__ float sIn[ICC][8][405];

    const int t = threadIdx.x;
    const int bx = blockIdx.x;
    const int twi = bx % NTW;
    const int thi = (bx / NTW) % NTH;
    const int tdi = bx / (NTW * NTH);
    const int ocBase = blockIdx.y * Q;
    const int icStart = blockIdx.z * ICB;

    const int d = t >> 6;          // 0..3 (wave-uniform)
    const int h = (t >> 3) & 7;    // 0..7
    const int w = t & 7;           // 0..7

    float acc[Q];
    #pragma unroll
    for (int j = 0; j < Q; ++j) acc[j] = (KS == 1) ? bias[ocBase + j] : 0.0f;

    const int id0 = 2 * (tdi * 4) - 1;
    const int ih0 = 2 * (thi * 8) - 1;
    const int iw0 = 2 * (twi * 8) - 1;

    #pragma unroll 1
    for (int ic0 = icStart; ic0 < icStart + ICB; ic0 += ICC) {
        __syncthreads();
        for (int p = t; p < ICC * 3240; p += 256) {
            int icc = p / 3240;
            int r   = p - icc * 3240;
            int li  = r / 324;
            int r2  = r - li * 324;
            int lh  = r2 / 18;
            int lw  = r2 - lh * 18;
            int gd = id0 + li, gh = ih0 + lh, gw = iw0 + lw;
            float v = 0.0f;
            if ((unsigned)gd < (unsigned)IND && (unsigned)gh < (unsigned)IND &&
                (unsigned)gw < (unsigned)IND)
                v = in[((ic0 + icc) * IND + gd) * IND * IND + gh * IND + gw];
            sIn[icc][((li & 1) << 2) | ((lh & 1) << 1) | (lw & 1)]
               [(li >> 1) * 81 + (lh >> 1) * 9 + (lw >> 1)] = v;
        }
        __syncthreads();
        #pragma unroll 1
        for (int icc = 0; icc < ICC; ++icc) {
            const int ic = ic0 + icc;
            #pragma unroll 1
            for (int kd = 0; kd < 4; ++kd) {
                #pragma unroll
                for (int kh = 0; kh < 4; ++kh)
                #pragma unroll
                for (int kw = 0; kw < 4; ++kw) {
                    const float iv = sIn[icc][((kd & 1) << 2) | ((kh & 1) << 1) | (kw & 1)]
                        [(d + (kd >> 1)) * 81 + (h + (kh >> 1)) * 9 + (w + (kw >> 1))];
                    const float* __restrict__ wr =
                        wT + (ic * 64 + (kd * 16 + kh * 4 + kw)) * OC + ocBase;
                    #pragma unroll
                    for (int j = 0; j < Q; ++j) acc[j] = fmaf(iv, wr[j], acc[j]);
                }
            }
        }
    }

    const int od = tdi * 4 + d;
    const int oh = thi * 8 + h;
    const int ow = twi * 8 + w;
    float* __restrict__ ob = out + (size_t)blockIdx.z * (OC * OUTD * OUTD * OUTD);
    #pragma unroll
    for (int j = 0; j < Q; ++j) {
        float v = acc[j];
        if (RELU && KS == 1) v = fmaxf(v, 0.0f);
        ob[((ocBase + j) * OUTD + od) * OUTD * OUTD + oh * OUTD + ow] = v;
    }
}

// ---------------------------------------------------------------------------
// ConvTranspose3d k=4 s=2 p=1 (one batch). out[o] += in[i]*w[k], o = 2i+k-1.
// Block: 8x8x8 out tile, Q oc. Wave q: (h,w)-parity (q>>1,q&1) (SGPR-hoisted);
// lane: (d2,h2,w2); thread covers d-parity pd in {0,1}: acc[2][Q]. KS as conv_sw.
template<int IC, int OC, int IND, bool RELU, int ICC, int Q, int KS>
__global__ __launch_bounds__(256)
void deconv_sw(const float* __restrict__ in, const float* __restrict__ dwT,
               const float* __restrict__ bias, float* __restrict__ out)
{
    constexpr int OUTD = IND * 2;
    constexpr int NT = OUTD / 8;
    constexpr int ICB = IC / KS;
    __shared__ float sIn[ICC][216];      // 6x6x6 per ic

    const int t = threadIdx.x;
    const int bx = blockIdx.x;
    const int twi = bx % NT;
    const int thi = (bx / NT) % NT;
    const int tdi = bx / (NT * NT);
    const int ocBase = blockIdx.y * Q;
    const int icStart = blockIdx.z * ICB;

    const int qv = __builtin_amdgcn_readfirstlane(t >> 6);  // wave id, uniform
    const int ph = qv >> 1, pw = qv & 1;
    const int l  = t & 63;
    const int d2 = l >> 4;           // 0..3
    const int h2 = (l >> 2) & 3;     // 0..3
    const int w2 = l & 3;            // 0..3

    float acc[2][Q];
    #pragma unroll
    for (int j = 0; j < Q; ++j) {
        float bv = (KS == 1) ? bias[ocBase + j] : 0.0f;
        acc[0][j] = bv; acc[1][j] = bv;
    }

    const int ibd = 4 * tdi - 1;
    const int ibh = 4 * thi - 1;
    const int ibw = 4 * twi - 1;

    #pragma unroll 1
    for (int ic0 = icStart; ic0 < icStart + ICB; ic0 += ICC) {
        __syncthreads();
        for (int p = t; p < ICC * 216; p += 256) {
            int icc = p / 216;
            int r   = p - icc * 216;
            int li  = r / 36;
            int r2  = r - li * 36;
            int lh  = r2 / 6;
            int lw  = r2 - lh * 6;
            int gd = ibd + li, gh = ibh + lh, gw = ibw + lw;
            float v = 0.0f;
            if ((unsigned)gd < (unsigned)IND && (unsigned)gh < (unsigned)IND &&
                (unsigned)gw < (unsigned)IND)
                v = in[((ic0 + icc) * IND + gd) * IND * IND + gh * IND + gw];
            sIn[icc][r] = v;
        }
        __syncthreads();
        #pragma unroll 1
        for (int icc = 0; icc < ICC; ++icc) {
            const int ic = ic0 + icc;
            #pragma unroll
            for (int pd = 0; pd < 2; ++pd)
            #pragma unroll
            for (int sdl = 0; sdl < 2; ++sdl)
            #pragma unroll
            for (int shl = 0; shl < 2; ++shl)
            #pragma unroll
            for (int swl = 0; swl < 2; ++swl) {
                const int td_ = (sdl ? 1 : 3) - pd;     // uniform
                const int th_ = (shl ? 1 : 3) - ph;
                const int tw_ = (swl ? 1 : 3) - pw;
                const int tap = td_ * 16 + th_ * 4 + tw_;
                const float iv = sIn[icc][(d2 + pd + sdl) * 36 + (h2 + ph + shl) * 6
                                          + (w2 + pw + swl)];
                const float* __restrict__ wr = dwT + (ic * 64 + tap) * OC + ocBase;
                #pragma unroll
                for (int j = 0; j < Q; ++j) acc[pd][j] = fmaf(iv, wr[j], acc[pd][j]);
            }
        }
    }

    float* __restrict__ ob = out + (size_t)blockIdx.z * (OC * OUTD * OUTD * OUTD);
    #pragma unroll
    for (int pd = 0; pd < 2; ++pd) {
        const int od = tdi * 8 + 2 * d2 + pd;
        const int oh = thi * 8 + 2 * h2 + ph;
        const int ow = twi * 8 + 2 * w2 + pw;
        #pragma unroll
        for (int j = 0; j < Q; ++j) {
            float v = acc[pd][j];
            if (RELU && KS == 1) v = fmaxf(v, 0.0f);
            ob[((ocBase + j) * OUTD + od) * OUTD * OUTD + oh * OUTD + ow] = v;
        }
    }
}

// ---------------------------------------------------------------------------
// out[i] = maybe_relu(p[i] + p[n+i] + bias[i >> VOLSHIFT]), float4-wide.
template<bool RELU, int VOLSHIFT>
__global__ __launch_bounds__(256)
void reduce2_bias(const float* __restrict__ p, const float* __restrict__ bias,
                  float* __restrict__ out, int n)
{
    int i = (blockIdx.x * 256 + threadIdx.x) * 4;
    if (i >= n) return;
    float4 a = *(const float4*)&p[i];
    float4 b = *(const float4*)&p[n + i];
    float bv = bias[i >> VOLSHIFT];
    float4 r;
    r.x = a.x + b.x + bv; r.y = a.y + b.y + bv;
    r.z = a.z + b.z + bv; r.w = a.w + b.w + bv;
    if (RELU) {
        r.x = fmaxf(r.x, 0.0f); r.y = fmaxf(r.y, 0.0f);
        r.z = fmaxf(r.z, 0.0f); r.w = fmaxf(r.w, 0.0f);
    }
    *(float4*)&out[i] = r;
}

// ---------------------------------------------------------------------------
// Fused (deconv3 . conv1x1), one batch: dwe[ic*64+tap], scalar be.
// Thread: 4x4x4 output block; inputs -> registers; 512 FMAs/ic; SCALAR stores
// (out = d_out+1+..., never 16B-aligned).
__global__ __launch_bounds__(256)
void deconv_final_sw(const float* __restrict__ in, const float* __restrict__ dwe,
                     const float* __restrict__ beP, float* __restrict__ out)
{
    constexpr int IC = 128, IND = 64, OUTD = 128, ICC = 2;
    __shared__ float sIn[ICC][3240];     // 10 x 18 x 18, row stride 18

    const int t = threadIdx.x;
    const int bx = blockIdx.x;           // 8 d-tiles x 4 h x 4 w
    const int bw = bx & 3;
    const int bh = (bx >> 2) & 3;
    const int bd = bx >> 4;

    const int td_ = t >> 6;              // 0..3
    const int th_ = (t >> 3) & 7;        // 0..7
    const int tw_ = t & 7;               // 0..7

    const int gd0 = 8 * bd - 1;
    const int gh0 = 16 * bh - 1;
    const int gw0 = 16 * bw - 1;

    float acc[4][4][4];
    #pragma unroll
    for (int a = 0; a < 4; ++a)
        #pragma unroll
        for (int bq = 0; bq < 4; ++bq)
            #pragma unroll
            for (int c = 0; c < 4; ++c) acc[a][bq][c] = 0.0f;

    // (il, k, ol) pair table for one dim: ol = 2*il + k - 3
    constexpr int PI[8] = {0,1,1,1,2,2,2,3};
    constexpr int PK[8] = {3,1,2,3,0,1,2,0};
    constexpr int PO[8] = {0,0,1,2,1,2,3,3};

    #pragma unroll 1
    for (int ic0 = 0; ic0 < IC; ic0 += ICC) {
        __syncthreads();
        for (int p = t; p < ICC * 3240; p += 256) {
            int icc = p / 3240;
            int r   = p - icc * 3240;
            int li  = r / 324;
            int r2  = r - li * 324;
            int lh  = r2 / 18;
            int lw  = r2 - lh * 18;
            int gd = gd0 + li, gh = gh0 + lh, gw = gw0 + lw;
            float v = 0.0f;
            if ((unsigned)gd < (unsigned)IND && (unsigned)gh < (unsigned)IND &&
                (unsigned)gw < (unsigned)IND)
                v = in[((ic0 + icc) * IND + gd) * IND * IND + gh * IND + gw];
            sIn[icc][r] = v;
        }
        __syncthreads();
        #pragma unroll 1
        for (int icc = 0; icc < ICC; ++icc) {
            const int ic = ic0 + icc;
            const float* __restrict__ wv = dwe + ic * 64;   // uniform -> s_load
            float riv[4][4][4];
            #pragma unroll
            for (int id = 0; id < 4; ++id)
                #pragma unroll
                for (int ih = 0; ih < 4; ++ih) {
                    const int off = (2 * td_ + id) * 324 + (2 * th_ + ih) * 18 + 2 * tw_;
                    const float2 r01 = *(const float2*)&sIn[icc][off];
                    const float2 r23 = *(const float2*)&sIn[icc][off + 2];
                    riv[id][ih][0] = r01.x; riv[id][ih][1] = r01.y;
                    riv[id][ih][2] = r23.x; riv[id][ih][3] = r23.y;
                }
            #pragma unroll
            for (int a = 0; a < 8; ++a)
                #pragma unroll
                for (int bq = 0; bq < 8; ++bq)
                    #pragma unroll
                    for (int c = 0; c < 8; ++c)
                        acc[PO[a]][PO[bq]][PO[c]] =
                            fmaf(riv[PI[a]][PI[bq]][PI[c]],
                                 wv[PK[a] * 16 + PK[bq] * 4 + PK[c]],
                                 acc[PO[a]][PO[bq]][PO[c]]);
        }
    }

    const float be = *beP;
    #pragma unroll
    for (int a = 0; a < 4; ++a)
        #pragma unroll
        for (int bq = 0; bq < 4; ++bq) {
            const int od = 16 * bd + 4 * td_ + a;
            const int oh = 32 * bh + 4 * th_ + bq;
            const int ow = 32 * bw + 4 * tw_;
            float* orow = &out[(od * OUTD + oh) * OUTD + ow];
            orow[0] = acc[a][bq][0] + be;
            orow[1] = acc[a][bq][1] + be;
            orow[2] = acc[a][bq][2] + be;
            orow[3] = acc[a][bq][3] + be;
        }
}

// ---------------------------------------------------------------------------
__global__ void esq_kernel(const float* __restrict__ emb, float* __restrict__ eSq)
{
    int k = blockIdx.x * 256 + threadIdx.x;
    if (k < 512) {
        float s = 0.0f;
        #pragma unroll
        for (int e = 0; e < 64; ++e) { float v = emb[k * 64 + e]; s += v * v; }
        eSq[k] = s;
    }
}

// dwe[ic*64+tap] = sum_c dw3[ic][c][tap] * wo[c];  be = bo + sum_c wo[c]*db3[c]
__global__ void fold_kernel(const float* __restrict__ dw3, const float* __restrict__ wo,
                            const float* __restrict__ db3, const float* __restrict__ bo,
                            float* __restrict__ dwe, float* __restrict__ beP)
{
    int idx = blockIdx.x * 256 + threadIdx.x;   // 8192 = 128 ic x 64 tap
    int ic = idx >> 6, tap = idx & 63;
    float s = 0.0f;
    for (int c = 0; c < 128; ++c) s += dw3[(ic * 128 + c) * 64 + tap] * wo[c];
    dwe[idx] = s;
    if (idx == 0) {
        float bb = bo[0];
        for (int c = 0; c < 128; ++c) bb += wo[c] * db3[c];
        *beP = bb;
    }
}

__global__ void zero_kernel(float* __restrict__ p)
{
    if (threadIdx.x == 0) p[0] = 0.0f;
}

// One batch: 16384 code-vectors. One lane per vector; k-range split across the
// 4 waves. dist mimics reference rounding: (||f||^2 + ||e_k||^2) - 2 f.e_k,
// first-min tie-break (matches jnp.argmin semantics incl. its quantization).
__global__ __launch_bounds__(256)
void vq_kernel(const float* __restrict__ h3, const float* __restrict__ emb,
               const float* __restrict__ eSq, float* __restrict__ q,
               float* __restrict__ lossAcc)
{
    __shared__ float sDist[4][64];
    __shared__ int   sIdx[4][64];
    const int t = threadIdx.x;
    const int vec = blockIdx.x * 64 + (t & 63);   // < 16384
    const int kq = t >> 6;
    const int cg = vec & 3;
    const int spat = vec >> 2;                    // 0..4095
    const int base = (cg * 64) * 4096 + spat;

    float v[64];
    #pragma unroll
    for (int e = 0; e < 64; ++e) v[e] = h3[base + e * 4096];

    float fSq = 0.0f;
    #pragma unroll
    for (int e = 0; e < 64; ++e) fSq += v[e] * v[e];

    float best = 1e30f; int bidx = 0;
    const int k0 = __builtin_amdgcn_readfirstlane(kq) * 128;
    for (int kk = 0; kk < 128; ++kk) {
        const int k = k0 + kk;
        const float* er = emb + k * 64;
        float d0 = 0, d1 = 0, d2 = 0, d3 = 0;
        #pragma unroll
        for (int e = 0; e < 64; e += 4) {
            d0 += v[e]     * er[e];
            d1 += v[e + 1] * er[e + 1];
            d2 += v[e + 2] * er[e + 2];
            d3 += v[e + 3] * er[e + 3];
        }
        const float s1 = fSq + eSq[k];
        const float dist = s1 - 2.0f * ((d0 + d1) + (d2 + d3));
        if (dist < best) { best = dist; bidx = k; }
    }
    sDist[kq][t & 63] = best;
    sIdx[kq][t & 63]  = bidx;
    __syncthreads();
    if (t < 64) {
        float bd = sDist[0][t]; int bi = sIdx[0][t];
        #pragma unroll
        for (int j = 1; j < 4; ++j) {
            float d = sDist[j][t]; int i2 = sIdx[j][t];
            if (d < bd || (d == bd && i2 < bi)) { bd = d; bi = i2; }
        }
        const float* er = emb + bi * 64;
        float ls = 0.0f;
        #pragma unroll
        for (int e = 0; e < 64; ++e) {
            float qe = er[e];
            q[base + e * 4096] = qe;
            float df = qe - v[e];
            ls += df * df;
        }
        #pragma unroll
        for (int off = 32; off > 0; off >>= 1) ls += __shfl_down(ls, off);
        if (t == 0) atomicAdd(lossAcc, ls);
    }
}

__global__ void loss_final(const float* __restrict__ lossAcc, float* __restrict__ out)
{
    // loss = (1 + 0.25) * mean((q-h)^2), mean over 2*16384*64 elements
    out[0] = 1.25f * lossAcc[0] / 2097152.0f;
}

// ---------------------------------------------------------------------------
extern "C" void kernel_launch(void* const* d_in, const int* in_sizes, int n_in,
                              void* d_out, int out_size, void* d_ws, size_t ws_size,
                              hipStream_t stream)
{
    (void)in_sizes; (void)n_in; (void)out_size; (void)ws_size;
    const float* x   = (const float*)d_in[0];
    const float* w1  = (const float*)d_in[1];
    const float* b1  = (const float*)d_in[2];
    const float* w2  = (const float*)d_in[3];
    const float* b2  = (const float*)d_in[4];
    const float* w3  = (const float*)d_in[5];
    const float* b3  = (const float*)d_in[6];
    const float* dw1 = (const float*)d_in[7];
    const float* db1 = (const float*)d_in[8];
    const float* dw2 = (const float*)d_in[9];
    const float* db2 = (const float*)d_in[10];
    const float* dw3 = (const float*)d_in[11];
    const float* db3 = (const float*)d_in[12];
    const float* wo  = (const float*)d_in[13];
    const float* bo  = (const float*)d_in[14];
    const float* emb = (const float*)d_in[15];

    // Workspace layout (floats), peak ~56.6M floats = 227 MB:
    float* ws   = (float*)d_ws;
    float* A    = ws;                    // 33,554,432  h1 / split-K partials / r2
    float* Bb   = A + 33554432;          //  8,388,608  h2 / r1
    float* C    = Bb + 8388608;          //  1,048,576  h3
    float* D    = C + 1048576;           //  1,048,576  q
    float* wT1  = D + 1048576;           //      8,192
    float* wT2  = wT1 + 8192;            //  2,097,152
    float* wT3  = wT2 + 2097152;         //  4,194,304
    float* dwT1 = wT3 + 4194304;         //  4,194,304
    float* dwT2 = dwT1 + 4194304;        //  2,097,152
    float* dwe  = dwT2 + 2097152;        //      8,192
    float* eSq  = dwe + 8192;            //        512
    float* lossAcc = eSq + 512;          //          1
    float* beP  = lossAcc + 1;           //          1

    float* outLoss = (float*)d_out;
    float* outR    = (float*)d_out + 1;

    zero_kernel<<<dim3(1), 64, 0, stream>>>(lossAcc);

    // weight prep (once; reused by both batches)
    repack_w<1,   128, false><<<dim3(32),    256, 0, stream>>>(w1,  wT1);
    repack_w<128, 256, false><<<dim3(8192),  256, 0, stream>>>(w2,  wT2);
    repack_w<256, 256, false><<<dim3(16384), 256, 0, stream>>>(w3,  wT3);
    repack_w<256, 256, true ><<<dim3(16384), 256, 0, stream>>>(dw1, dwT1);
    repack_w<256, 128, true ><<<dim3(8192),  256, 0, stream>>>(dw2, dwT2);
    fold_kernel<<<dim3(32), 256, 0, stream>>>(dw3, wo, db3, bo, dwe, beP);
    esq_kernel<<<dim3(2), 256, 0, stream>>>(emb, eSq);

    for (int b = 0; b < 2; ++b) {
        const float* xb = x + (size_t)b * 2097152;       // [1,128,128,128]
        float* rb = outR + (size_t)b * 2097152;          // [1,128,128,128]

        // encoder
        conv_sw<1,   128, 128, true,  1, 64, 1><<<dim3(1024, 2, 1), 256, 0, stream>>>(xb, wT1, b1, A);
        conv_sw<128, 256, 64,  true,  2, 32, 1><<<dim3(128,  8, 1), 256, 0, stream>>>(A,  wT2, b2, Bb);
        // conv3 split-K=2: partials into A (h1 dead), then reduce+bias (no relu)
        conv_sw<256, 256, 32,  false, 2, 16, 2><<<dim3(16,  16, 2), 256, 0, stream>>>(Bb, wT3, b3, A);
        reduce2_bias<false, 12><<<dim3(1024), 256, 0, stream>>>(A, b3, C, 1048576);

        vq_kernel<<<dim3(256), 256, 0, stream>>>(C, emb, eSq, D, lossAcc);

        // deconv1 split-K=2: partials into A, then reduce+bias+relu -> Bb
        deconv_sw<256, 256, 16, true, 8, 32, 2><<<dim3(64,  8, 2), 256, 0, stream>>>(D, dwT1, db1, A);
        reduce2_bias<true, 15><<<dim3(8192), 256, 0, stream>>>(A, db1, Bb, 8388608);

        deconv_sw<256, 128, 32, true, 8, 32, 1><<<dim3(512, 4, 1), 256, 0, stream>>>(Bb, dwT2, db2, A);
        deconv_final_sw<<<dim3(128), 256, 0, stream>>>(A, dwe, beP, rb);
    }

    loss_final<<<dim3(1), 1, 0, stream>>>(lossAcc, outLoss);
}

// Round 5
// 12777.299 us; speedup vs baseline: 1.4367x; 1.1242x over previous
//
#include <hip/hip_runtime.h>

// VQ-VAE fwd on MI355X, fp32, scalar-weight (SMEM) direct conv/deconv.
//  - deconv3 (1.1 TFLOP) folded into the 1x1 output conv -> 8.6 GF fused kernel.
//  - lane = 1 output point, Q oc in registers; weights wave-uniform
//    (repacked [ic][tap][oc]) -> s_load, no LDS traffic for weights.
//  - R5: conv2 Q=64 (2x FMA density) + split-K=4 via atomicAdd (2048 blocks,
//    8/CU). conv3 KS=8, deconv1 KS=4 likewise. bias_init + relu passes.
//    R4 measured conv2: occ 39.7% (grid 4/CU), VALUBusy 69%, ~1 non-FMA VALU
//    cycle per FMA cycle -> density + occupancy are the levers.

// ---------------------------------------------------------------------------
// Repack weights to wT[(ic*64 + tap)*OC + oc].
// TR=false: src is conv layout (OC,IC,4,4,4). TR=true: deconv layout (IC,OC,4,4,4).
template<int IC, int OC, bool TR>
__global__ __launch_bounds__(256)
void repack_w(const float* __restrict__ src, float* __restrict__ dst)
{
    int idx = blockIdx.x * 256 + threadIdx.x;
    if (idx >= IC * OC * 64) return;
    int oc  = idx % OC;
    int rem = idx / OC;
    int tap = rem % 64;
    int ic  = rem / 64;
    float v = TR ? src[(ic * OC + oc) * 64 + tap]
                 : src[(oc * IC + ic) * 64 + tap];
    dst[idx] = v;
}

// ---------------------------------------------------------------------------
// out[i] = bias[i >> VOLSHIFT], float4-wide (VOLSHIFT >= 2 so bv uniform in 4).
template<int VOLSHIFT>
__global__ __launch_bounds__(256)
void bias_init(const float* __restrict__ bias, float* __restrict__ out, int n)
{
    int i = (blockIdx.x * 256 + threadIdx.x) * 4;
    if (i >= n) return;
    float bv = bias[i >> VOLSHIFT];
    float4 r; r.x = bv; r.y = bv; r.z = bv; r.w = bv;
    *(float4*)&out[i] = r;
}

__global__ __launch_bounds__(256)
void relu_inplace(float* __restrict__ p, int n)
{
    int i = (blockIdx.x * 256 + threadIdx.x) * 4;
    if (i >= n) return;
    float4 a = *(const float4*)&p[i];
    a.x = fmaxf(a.x, 0.0f); a.y = fmaxf(a.y, 0.0f);
    a.z = fmaxf(a.z, 0.0f); a.w = fmaxf(a.w, 0.0f);
    *(float4*)&p[i] = a;
}

// ---------------------------------------------------------------------------
// conv k=4 s=2 p=1 (one batch). Block: 4x8x8 out spatial, Q oc. Thread: 1 point.
// Input tile 10x18x18 per ic, parity-deinterleaved: [8 parity][5*9*9] (stride 9).
// ATOMIC: blockIdx.z selects an IC/KS chunk; partials atomicAdd'ed into out
// (bias pre-initialized by bias_init; relu applied by relu_inplace after).
template<int IC, int OC, int IND, bool RELU, int ICC, int Q, int KS, bool ATOMIC>
__global__ __launch_bounds__(256)
void conv_sw(const float* __restrict__ in, const float* __restrict__ wT,
             const float* __restrict__ bias, float* __restrict__ out)
{
    constexpr int OUTD = IND / 2;
    constexpr int NTW = OUTD / 8, NTH = OUTD / 8;
    constexpr int ICB = IC / KS;
    __shared__ float sIn[ICC][8][405];

    const int t = threadIdx.x;
    const int bx = blockIdx.x;
    const int twi = bx % NTW;
    const int thi = (bx / NTW) % NTH;
    const int tdi = bx / (NTW * NTH);
    const int ocBase = blockIdx.y * Q;
    const int icStart = blockIdx.z * ICB;

    const int d = t >> 6;          // 0..3 (wave-uniform)
    const int h = (t >> 3) & 7;    // 0..7
    const int w = t & 7;           // 0..7

    float acc[Q];
    #pragma unroll
    for (int j = 0; j < Q; ++j) acc[j] = ATOMIC ? 0.0f : bias[ocBase + j];

    const int id0 = 2 * (tdi * 4) - 1;
    const int ih0 = 2 * (thi * 8) - 1;
    const int iw0 = 2 * (twi * 8) - 1;

    #pragma unroll 1
    for (int ic0 = icStart; ic0 < icStart + ICB; ic0 += ICC) {
        __syncthreads();
        for (int p = t; p < ICC * 3240; p += 256) {
            int icc = p / 3240;
            int r   = p - icc * 3240;
            int li  = r / 324;
            int r2  = r - li * 324;
            int lh  = r2 / 18;
            int lw  = r2 - lh * 18;
            int gd = id0 + li, gh = ih0 + lh, gw = iw0 + lw;
            float v = 0.0f;
            if ((unsigned)gd < (unsigned)IND && (unsigned)gh < (unsigned)IND &&
                (unsigned)gw < (unsigned)IND)
                v = in[((ic0 + icc) * IND + gd) * IND * IND + gh * IND + gw];
            sIn[icc][((li & 1) << 2) | ((lh & 1) << 1) | (lw & 1)]
               [(li >> 1) * 81 + (lh >> 1) * 9 + (lw >> 1)] = v;
        }
        __syncthreads();
        #pragma unroll 1
        for (int icc = 0; icc < ICC; ++icc) {
            const int ic = ic0 + icc;
            #pragma unroll 1
            for (int kd = 0; kd < 4; ++kd) {
                #pragma unroll
                for (int kh = 0; kh < 4; ++kh)
                #pragma unroll
                for (int kw = 0; kw < 4; ++kw) {
                    const float iv = sIn[icc][((kd & 1) << 2) | ((kh & 1) << 1) | (kw & 1)]
                        [(d + (kd >> 1)) * 81 + (h + (kh >> 1)) * 9 + (w + (kw >> 1))];
                    const float* __restrict__ wr =
                        wT + (ic * 64 + (kd * 16 + kh * 4 + kw)) * OC + ocBase;
                    #pragma unroll
                    for (int j = 0; j < Q; ++j) acc[j] = fmaf(iv, wr[j], acc[j]);
                }
            }
        }
    }

    const int od = tdi * 4 + d;
    const int oh = thi * 8 + h;
    const int ow = twi * 8 + w;
    #pragma unroll
    for (int j = 0; j < Q; ++j) {
        const int oi = ((ocBase + j) * OUTD + od) * OUTD * OUTD + oh * OUTD + ow;
        if (ATOMIC) {
            atomicAdd(&out[oi], acc[j]);
        } else {
            float v = acc[j];
            if (RELU) v = fmaxf(v, 0.0f);
            out[oi] = v;
        }
    }
}

// ---------------------------------------------------------------------------
// ConvTranspose3d k=4 s=2 p=1 (one batch). out[o] += in[i]*w[k], o = 2i+k-1.
// Block: 8x8x8 out tile, Q oc. Wave q: (h,w)-parity (q>>1,q&1) (SGPR-hoisted);
// lane: (d2,h2,w2); thread covers d-parity pd in {0,1}: acc[2][Q]. ATOMIC as conv.
template<int IC, int OC, int IND, bool RELU, int ICC, int Q, int KS, bool ATOMIC>
__global__ __launch_bounds__(256)
void deconv_sw(const float* __restrict__ in, const float* __restrict__ dwT,
               const float* __restrict__ bias, float* __restrict__ out)
{
    constexpr int OUTD = IND * 2;
    constexpr int NT = OUTD / 8;
    constexpr int ICB = IC / KS;
    __shared__ float sIn[ICC][216];      // 6x6x6 per ic

    const int t = threadIdx.x;
    const int bx = blockIdx.x;
    const int twi = bx % NT;
    const int thi = (bx / NT) % NT;
    const int tdi = bx / (NT * NT);
    const int ocBase = blockIdx.y * Q;
    const int icStart = blockIdx.z * ICB;

    const int qv = __builtin_amdgcn_readfirstlane(t >> 6);  // wave id, uniform
    const int ph = qv >> 1, pw = qv & 1;
    const int l  = t & 63;
    const int d2 = l >> 4;           // 0..3
    const int h2 = (l >> 2) & 3;     // 0..3
    const int w2 = l & 3;            // 0..3

    float acc[2][Q];
    #pragma unroll
    for (int j = 0; j < Q; ++j) {
        float bv = ATOMIC ? 0.0f : bias[ocBase + j];
        acc[0][j] = bv; acc[1][j] = bv;
    }

    const int ibd = 4 * tdi - 1;
    const int ibh = 4 * thi - 1;
    const int ibw = 4 * twi - 1;

    #pragma unroll 1
    for (int ic0 = icStart; ic0 < icStart + ICB; ic0 += ICC) {
        __syncthreads();
        for (int p = t; p < ICC * 216; p += 256) {
            int icc = p / 216;
            int r   = p - icc * 216;
            int li  = r / 36;
            int r2  = r - li * 36;
            int lh  = r2 / 6;
            int lw  = r2 - lh * 6;
            int gd = ibd + li, gh = ibh + lh, gw = ibw + lw;
            float v = 0.0f;
            if ((unsigned)gd < (unsigned)IND && (unsigned)gh < (unsigned)IND &&
                (unsigned)gw < (unsigned)IND)
                v = in[((ic0 + icc) * IND + gd) * IND * IND + gh * IND + gw];
            sIn[icc][r] = v;
        }
        __syncthreads();
        #pragma unroll 1
        for (int icc = 0; icc < ICC; ++icc) {
            const int ic = ic0 + icc;
            #pragma unroll
            for (int pd = 0; pd < 2; ++pd)
            #pragma unroll
            for (int sdl = 0; sdl < 2; ++sdl)
            #pragma unroll
            for (int shl = 0; shl < 2; ++shl)
            #pragma unroll
            for (int swl = 0; swl < 2; ++swl) {
                const int td_ = (sdl ? 1 : 3) - pd;     // uniform
                const int th_ = (shl ? 1 : 3) - ph;
                const int tw_ = (swl ? 1 : 3) - pw;
                const int tap = td_ * 16 + th_ * 4 + tw_;
                const float iv = sIn[icc][(d2 + pd + sdl) * 36 + (h2 + ph + shl) * 6
                                          + (w2 + pw + swl)];
                const float* __restrict__ wr = dwT + (ic * 64 + tap) * OC + ocBase;
                #pragma unroll
                for (int j = 0; j < Q; ++j) acc[pd][j] = fmaf(iv, wr[j], acc[pd][j]);
            }
        }
    }

    #pragma unroll
    for (int pd = 0; pd < 2; ++pd) {
        const int od = tdi * 8 + 2 * d2 + pd;
        const int oh = thi * 8 + 2 * h2 + ph;
        const int ow = twi * 8 + 2 * w2 + pw;
        #pragma unroll
        for (int j = 0; j < Q; ++j) {
            const int oi = ((ocBase + j) * OUTD + od) * OUTD * OUTD + oh * OUTD + ow;
            if (ATOMIC) {
                atomicAdd(&out[oi], acc[pd][j]);
            } else {
                float v = acc[pd][j];
                if (RELU) v = fmaxf(v, 0.0f);
                out[oi] = v;
            }
        }
    }
}

// ---------------------------------------------------------------------------
// Fused (deconv3 . conv1x1), one batch: dwe[ic*64+tap], scalar be.
// Thread: 4x4x4 output block; inputs -> registers; 512 FMAs/ic; SCALAR stores
// (out = d_out+1+..., never 16B-aligned).
__global__ __launch_bounds__(256)
void deconv_final_sw(const float* __restrict__ in, const float* __restrict__ dwe,
                     const float* __restrict__ beP, float* __restrict__ out)
{
    constexpr int IC = 128, IND = 64, OUTD = 128, ICC = 2;
    __shared__ float sIn[ICC][3240];     // 10 x 18 x 18, row stride 18

    const int t = threadIdx.x;
    const int bx = blockIdx.x;           // 8 d-tiles x 4 h x 4 w
    const int bw = bx & 3;
    const int bh = (bx >> 2) & 3;
    const int bd = bx >> 4;

    const int td_ = t >> 6;              // 0..3
    const int th_ = (t >> 3) & 7;        // 0..7
    const int tw_ = t & 7;               // 0..7

    const int gd0 = 8 * bd - 1;
    const int gh0 = 16 * bh - 1;
    const int gw0 = 16 * bw - 1;

    float acc[4][4][4];
    #pragma unroll
    for (int a = 0; a < 4; ++a)
        #pragma unroll
        for (int bq = 0; bq < 4; ++bq)
            #pragma unroll
            for (int c = 0; c < 4; ++c) acc[a][bq][c] = 0.0f;

    // (il, k, ol) pair table for one dim: ol = 2*il + k - 3
    constexpr int PI[8] = {0,1,1,1,2,2,2,3};
    constexpr int PK[8] = {3,1,2,3,0,1,2,0};
    constexpr int PO[8] = {0,0,1,2,1,2,3,3};

    #pragma unroll 1
    for (int ic0 = 0; ic0 < IC; ic0 += ICC) {
        __syncthreads();
        for (int p = t; p < ICC * 3240; p += 256) {
            int icc = p / 3240;
            int r   = p - icc * 3240;
            int li  = r / 324;
            int r2  = r - li * 324;
            int lh  = r2 / 18;
            int lw  = r2 - lh * 18;
            int gd = gd0 + li, gh = gh0 + lh, gw = gw0 + lw;
            float v = 0.0f;
            if ((unsigned)gd < (unsigned)IND && (unsigned)gh < (unsigned)IND &&
                (unsigned)gw < (unsigned)IND)
                v = in[((ic0 + icc) * IND + gd) * IND * IND + gh * IND + gw];
            sIn[icc][r] = v;
        }
        __syncthreads();
        #pragma unroll 1
        for (int icc = 0; icc < ICC; ++icc) {
            const int ic = ic0 + icc;
            const float* __restrict__ wv = dwe + ic * 64;   // uniform -> s_load
            float riv[4][4][4];
            #pragma unroll
            for (int id = 0; id < 4; ++id)
                #pragma unroll
                for (int ih = 0; ih < 4; ++ih) {
                    const int off = (2 * td_ + id) * 324 + (2 * th_ + ih) * 18 + 2 * tw_;
                    const float2 r01 = *(const float2*)&sIn[icc][off];
                    const float2 r23 = *(const float2*)&sIn[icc][off + 2];
                    riv[id][ih][0] = r01.x; riv[id][ih][1] = r01.y;
                    riv[id][ih][2] = r23.x; riv[id][ih][3] = r23.y;
                }
            #pragma unroll
            for (int a = 0; a < 8; ++a)
                #pragma unroll
                for (int bq = 0; bq < 8; ++bq)
                    #pragma unroll
                    for (int c = 0; c < 8; ++c)
                        acc[PO[a]][PO[bq]][PO[c]] =
                            fmaf(riv[PI[a]][PI[bq]][PI[c]],
                                 wv[PK[a] * 16 + PK[bq] * 4 + PK[c]],
                                 acc[PO[a]][PO[bq]][PO[c]]);
        }
    }

    const float be = *beP;
    #pragma unroll
    for (int a = 0; a < 4; ++a)
        #pragma unroll
        for (int bq = 0; bq < 4; ++bq) {
            const int od = 16 * bd + 4 * td_ + a;
            const int oh = 32 * bh + 4 * th_ + bq;
            const int ow = 32 * bw + 4 * tw_;
            float* orow = &out[(od * OUTD + oh) * OUTD + ow];
            orow[0] = acc[a][bq][0] + be;
            orow[1] = acc[a][bq][1] + be;
            orow[2] = acc[a][bq][2] + be;
            orow[3] = acc[a][bq][3] + be;
        }
}

// ---------------------------------------------------------------------------
__global__ void esq_kernel(const float* __restrict__ emb, float* __restrict__ eSq)
{
    int k = blockIdx.x * 256 + threadIdx.x;
    if (k < 512) {
        float s = 0.0f;
        #pragma unroll
        for (int e = 0; e < 64; ++e) { float v = emb[k * 64 + e]; s += v * v; }
        eSq[k] = s;
    }
}

// dwe[ic*64+tap] = sum_c dw3[ic][c][tap] * wo[c];  be = bo + sum_c wo[c]*db3[c]
__global__ void fold_kernel(const float* __restrict__ dw3, const float* __restrict__ wo,
                            const float* __restrict__ db3, const float* __restrict__ bo,
                            float* __restrict__ dwe, float* __restrict__ beP)
{
    int idx = blockIdx.x * 256 + threadIdx.x;   // 8192 = 128 ic x 64 tap
    int ic = idx >> 6, tap = idx & 63;
    float s = 0.0f;
    for (int c = 0; c < 128; ++c) s += dw3[(ic * 128 + c) * 64 + tap] * wo[c];
    dwe[idx] = s;
    if (idx == 0) {
        float bb = bo[0];
        for (int c = 0; c < 128; ++c) bb += wo[c] * db3[c];
        *beP = bb;
    }
}

__global__ void zero_kernel(float* __restrict__ p)
{
    if (threadIdx.x == 0) p[0] = 0.0f;
}

// One batch: 16384 code-vectors. One lane per vector; k-range split across the
// 4 waves. dist mimics reference rounding: (||f||^2 + ||e_k||^2) - 2 f.e_k,
// first-min tie-break (matches jnp.argmin semantics incl. its quantization).
__global__ __launch_bounds__(256)
void vq_kernel(const float* __restrict__ h3, const float* __restrict__ emb,
               const float* __restrict__ eSq, float* __restrict__ q,
               float* __restrict__ lossAcc)
{
    __shared__ float sDist[4][64];
    __shared__ int   sIdx[4][64];
    const int t = threadIdx.x;
    const int vec = blockIdx.x * 64 + (t & 63);   // < 16384
    const int kq = t >> 6;
    const int cg = vec & 3;
    const int spat = vec >> 2;                    // 0..4095
    const int base = (cg * 64) * 4096 + spat;

    float v[64];
    #pragma unroll
    for (int e = 0; e < 64; ++e) v[e] = h3[base + e * 4096];

    float fSq = 0.0f;
    #pragma unroll
    for (int e = 0; e < 64; ++e) fSq += v[e] * v[e];

    float best = 1e30f; int bidx = 0;
    const int k0 = __builtin_amdgcn_readfirstlane(kq) * 128;
    for (int kk = 0; kk < 128; ++kk) {
        const int k = k0 + kk;
        const float* er = emb + k * 64;
        float d0 = 0, d1 = 0, d2 = 0, d3 = 0;
        #pragma unroll
        for (int e = 0; e < 64; e += 4) {
            d0 += v[e]     * er[e];
            d1 += v[e + 1] * er[e + 1];
            d2 += v[e + 2] * er[e + 2];
            d3 += v[e + 3] * er[e + 3];
        }
        const float s1 = fSq + eSq[k];
        const float dist = s1 - 2.0f * ((d0 + d1) + (d2 + d3));
        if (dist < best) { best = dist; bidx = k; }
    }
    sDist[kq][t & 63] = best;
    sIdx[kq][t & 63]  = bidx;
    __syncthreads();
    if (t < 64) {
        float bd = sDist[0][t]; int bi = sIdx[0][t];
        #pragma unroll
        for (int j = 1; j < 4; ++j) {
            float d = sDist[j][t]; int i2 = sIdx[j][t];
            if (d < bd || (d == bd && i2 < bi)) { bd = d; bi = i2; }
        }
        const float* er = emb + bi * 64;
        float ls = 0.0f;
        #pragma unroll
        for (int e = 0; e < 64; ++e) {
            float qe = er[e];
            q[base + e * 4096] = qe;
            float df = qe - v[e];
            ls += df * df;
        }
        #pragma unroll
        for (int off = 32; off > 0; off >>= 1) ls += __shfl_down(ls, off);
        if (t == 0) atomicAdd(lossAcc, ls);
    }
}

__global__ void loss_final(const float* __restrict__ lossAcc, float* __restrict__ out)
{
    // loss = (1 + 0.25) * mean((q-h)^2), mean over 2*16384*64 elements
    out[0] = 1.25f * lossAcc[0] / 2097152.0f;
}

// ---------------------------------------------------------------------------
extern "C" void kernel_launch(void* const* d_in, const int* in_sizes, int n_in,
                              void* d_out, int out_size, void* d_ws, size_t ws_size,
                              hipStream_t stream)
{
    (void)in_sizes; (void)n_in; (void)out_size; (void)ws_size;
    const float* x   = (const float*)d_in[0];
    const float* w1  = (const float*)d_in[1];
    const float* b1  = (const float*)d_in[2];
    const float* w2  = (const float*)d_in[3];
    const float* b2  = (const float*)d_in[4];
    const float* w3  = (const float*)d_in[5];
    const float* b3  = (const float*)d_in[6];
    const float* dw1 = (const float*)d_in[7];
    const float* db1 = (const float*)d_in[8];
    const float* dw2 = (const float*)d_in[9];
    const float* db2 = (const float*)d_in[10];
    const float* dw3 = (const float*)d_in[11];
    const float* db3 = (const float*)d_in[12];
    const float* wo  = (const float*)d_in[13];
    const float* bo  = (const float*)d_in[14];
    const float* emb = (const float*)d_in[15];

    // Workspace layout (floats), peak ~56.6M floats = 227 MB:
    float* ws   = (float*)d_ws;
    float* A    = ws;                    // 33,554,432  h1 / r2 (one batch)
    float* Bb   = A + 33554432;          //  8,388,608  h2 / r1
    float* C    = Bb + 8388608;          //  1,048,576  h3
    float* D    = C + 1048576;           //  1,048,576  q
    float* wT1  = D + 1048576;           //      8,192
    float* wT2  = wT1 + 8192;            //  2,097,152
    float* wT3  = wT2 + 2097152;         //  4,194,304
    float* dwT1 = wT3 + 4194304;         //  4,194,304
    float* dwT2 = dwT1 + 4194304;        //  2,097,152
    float* dwe  = dwT2 + 2097152;        //      8,192
    float* eSq  = dwe + 8192;            //        512
    float* lossAcc = eSq + 512;          //          1
    float* beP  = lossAcc + 1;           //          1

    float* outLoss = (float*)d_out;
    float* outR    = (float*)d_out + 1;

    zero_kernel<<<dim3(1), 64, 0, stream>>>(lossAcc);

    // weight prep (once; reused by both batches)
    repack_w<1,   128, false><<<dim3(32),    256, 0, stream>>>(w1,  wT1);
    repack_w<128, 256, false><<<dim3(8192),  256, 0, stream>>>(w2,  wT2);
    repack_w<256, 256, false><<<dim3(16384), 256, 0, stream>>>(w3,  wT3);
    repack_w<256, 256, true ><<<dim3(16384), 256, 0, stream>>>(dw1, dwT1);
    repack_w<256, 128, true ><<<dim3(8192),  256, 0, stream>>>(dw2, dwT2);
    fold_kernel<<<dim3(32), 256, 0, stream>>>(dw3, wo, db3, bo, dwe, beP);
    esq_kernel<<<dim3(2), 256, 0, stream>>>(emb, eSq);

    for (int b = 0; b < 2; ++b) {
        const float* xb = x + (size_t)b * 2097152;       // [1,128,128,128]
        float* rb = outR + (size_t)b * 2097152;          // [1,128,128,128]

        // conv1 (IC=1): direct, Q=64, 2048 blocks
        conv_sw<1, 128, 128, true, 1, 64, 1, false><<<dim3(1024, 2, 1), 256, 0, stream>>>(xb, wT1, b1, A);

        // conv2: Q=64, split-K=4 atomic (2048 blocks = 8/CU)
        bias_init<15><<<dim3(8192), 256, 0, stream>>>(b2, Bb, 8388608);
        conv_sw<128, 256, 64, false, 2, 64, 4, true><<<dim3(128, 4, 4), 256, 0, stream>>>(A, wT2, b2, Bb);
        relu_inplace<<<dim3(8192), 256, 0, stream>>>(Bb, 8388608);

        // conv3: Q=32, split-K=8 atomic (1024 blocks), no relu
        bias_init<12><<<dim3(1024), 256, 0, stream>>>(b3, C, 1048576);
        conv_sw<256, 256, 32, false, 2, 32, 8, true><<<dim3(16, 8, 8), 256, 0, stream>>>(Bb, wT3, b3, C);

        vq_kernel<<<dim3(256), 256, 0, stream>>>(C, emb, eSq, D, lossAcc);

        // deconv1: Q=32, split-K=4 atomic (2048 blocks)
        bias_init<15><<<dim3(8192), 256, 0, stream>>>(db1, Bb, 8388608);
        deconv_sw<256, 256, 16, false, 8, 32, 4, true><<<dim3(64, 8, 4), 256, 0, stream>>>(D, dwT1, db1, Bb);
        relu_inplace<<<dim3(8192), 256, 0, stream>>>(Bb, 8388608);

        // deconv2: direct (2048 blocks already)
        deconv_sw<256, 128, 32, true, 8, 32, 1, false><<<dim3(512, 4, 1), 256, 0, stream>>>(Bb, dwT2, db2, A);

        deconv_final_sw<<<dim3(128), 256, 0, stream>>>(A, dwe, beP, rb);
    }

    loss_final<<<dim3(1), 1, 0, stream>>>(lossAcc, outLoss);
}

// Round 6
// 9611.895 us; speedup vs baseline: 1.9098x; 1.3293x over previous
//
#include <hip/hip_runtime.h>

// VQ-VAE fwd on MI355X.
//  - Encoder + VQ: fp32 scalar-weight path (unchanged from R5; passing).
//  - Decoder (deconv1, deconv2): MFMA split-bf16 implicit GEMM (NEW, R6).
//    Per parity class p (8): C[oc,n] = sum_{sel,ic} W[p,sel,ic,oc] * X[ic,pos(n,sel)]
//    K ordered sel-major so a lane's 8 frag elems = 8 consecutive ics ->
//    one 16B load from channels-last bf16 arrays (hi/lo interleaved per 8-ic group).
//  - deconv3 folded into 1x1 output conv (fused final kernel, fp32, unchanged).

typedef short  s8v  __attribute__((ext_vector_type(8)));
typedef float  f4v  __attribute__((ext_vector_type(4)));

__device__ inline void bf16split(float v, unsigned short& h, unsigned short& l)
{
    unsigned u = __float_as_uint(v);
    unsigned hr = (u + 0x7FFFu + ((u >> 16) & 1u)) >> 16;   // RNE
    h = (unsigned short)hr;
    float hf = __uint_as_float(hr << 16);
    float r = v - hf;
    unsigned u2 = __float_as_uint(r);
    l = (unsigned short)((u2 + 0x7FFFu + ((u2 >> 16) & 1u)) >> 16);
}

// ---------------------------------------------------------------------------
// fp32 weight repack for scalar-weight convs: wT[(ic*64 + tap)*OC + oc].
template<int IC, int OC, bool TR>
__global__ __launch_bounds__(256)
void repack_w(const float* __restrict__ src, float* __restrict__ dst)
{
    int idx = blockIdx.x * 256 + threadIdx.x;
    if (idx >= IC * OC * 64) return;
    int oc  = idx % OC;
    int rem = idx / OC;
    int tap = rem % 64;
    int ic  = rem / 64;
    float v = TR ? src[(ic * OC + oc) * 64 + tap]
                 : src[(oc * IC + ic) * 64 + tap];
    dst[idx] = v;
}

// ---------------------------------------------------------------------------
// MFMA weight repack: dst interleaved [cs=(class*8+sel)][oc][icg][hi8|lo8] ushort.
// src = deconv weight (IC, OC, 4,4,4) fp32. tap_dim = (s?1:3) - p per dim.
template<int IC, int OC>
__global__ __launch_bounds__(256)
void repack_mfma(const float* __restrict__ src, unsigned short* __restrict__ dst)
{
    int idx = blockIdx.x * 256 + threadIdx.x;
    if (idx >= 64 * OC * IC) return;
    int ic  = idx % IC;
    int rem = idx / IC;
    int oc  = rem % OC;
    int cs  = rem / OC;
    int c = cs >> 3, s = cs & 7;
    int pd = (c >> 2) & 1, ph = (c >> 1) & 1, pw = c & 1;
    int sd = (s >> 2) & 1, sh = (s >> 1) & 1, sw = s & 1;
    int td = (sd ? 1 : 3) - pd;
    int th = (sh ? 1 : 3) - ph;
    int tw = (sw ? 1 : 3) - pw;
    int tap = td * 16 + th * 4 + tw;
    float w = src[(ic * OC + oc) * 64 + tap];
    unsigned short h, l;
    bf16split(w, h, l);
    size_t base = ((size_t)(cs * OC + oc) * (IC / 8) + (ic >> 3)) * 16 + (ic & 7);
    dst[base]     = h;
    dst[base + 8] = l;
}

// ---------------------------------------------------------------------------
// MFMA deconv k4s2p1, split-bf16. Block: 128oc x 128n (4 waves = 2wm x 2wn),
// wave: 4 M-tiles x 4 N-tiles of mfma_f32_16x16x32_bf16, K = 8 sels x IC ics.
// inx: channels-last bf16 [z][y][x][icg][hi8|lo8]; wx: repack_mfma layout.
// TOBF16: write channels-last bf16 hi/lo (feeds next MFMA deconv);
// else: write channels-first fp32. ReLU always. OOB -> zero-page redirect.
template<int IC, int OC, int IND, bool TOBF16>
__global__ __launch_bounds__(256, 2)
void deconv_mfma(const unsigned short* __restrict__ inx,
                 const unsigned short* __restrict__ wx,
                 const float* __restrict__ bias,
                 float* __restrict__ outF, unsigned short* __restrict__ outB,
                 const float* __restrict__ zpage)
{
    constexpr int OUTD = IND * 2;
    constexpr int XH  = IND / 16;       // x tiles per row (1 or 2)
    constexpr int NTY = 4 / XH;         // y rows per wave
    constexpr int YG  = IND / (2 * NTY);

    const int t  = threadIdx.x;
    const int l  = t & 63;
    const int wid = t >> 6;
    const int wm = wid >> 1;            // oc half
    const int wn = wid & 1;             // n half
    const int lm = l & 15;
    const int lg = l >> 4;

    const int yg  = blockIdx.x % YG;
    const int zb  = blockIdx.x / YG;
    const int cls = blockIdx.y;
    const int ocb = blockIdx.z;

    const int pd = (cls >> 2) & 1, ph = (cls >> 1) & 1, pw = cls & 1;

    const char* __restrict__ ibase = (const char*)inx;
    const char* __restrict__ wbase = (const char*)wx;
    const char* __restrict__ zb_c  = (const char*)zpage;

    f4v acc[4][4];
    #pragma unroll
    for (int m = 0; m < 4; ++m)
        #pragma unroll
        for (int n = 0; n < 4; ++n)
            acc[m][n] = (f4v){0.f, 0.f, 0.f, 0.f};

    #pragma unroll 1
    for (int s = 0; s < 8; ++s) {
        const int sd = (s >> 2) & 1, sh = (s >> 1) & 1, sw = s & 1;
        const int iz = zb + pd + sd - 1;
        const bool zbad = (unsigned)iz >= (unsigned)IND;

        const char* pA[4];
        #pragma unroll
        for (int m = 0; m < 4; ++m) {
            const int oc = ocb * 128 + wm * 64 + m * 16 + lm;
            pA[m] = wbase + ((size_t)((cls * 8 + s) * OC + oc) * (IC / 8) + lg) * 32;
        }
        const char* pB[4];
        #pragma unroll
        for (int n = 0; n < 4; ++n) {
            const int xh   = (XH == 2) ? (n & 1) : 0;
            const int yloc = (XH == 2) ? (n >> 1) : n;
            const int y2 = yg * (2 * NTY) + wn * NTY + yloc;
            const int iy = y2 + ph + sh - 1;
            const int x2 = xh * 16 + lm;
            const int ix = x2 + pw + sw - 1;
            const bool bad = zbad || ((unsigned)iy >= (unsigned)IND)
                                  || ((unsigned)ix >= (unsigned)IND);
            const char* p = ibase +
                ((size_t)((iz * IND + iy) * IND + ix) * (IC / 8) + lg) * 32;
            pB[n] = bad ? zb_c : p;
        }

        #pragma unroll 2
        for (int kb = 0; kb < IC / 32; ++kb) {
            s8v ah[4], al[4], bh[4], bl[4];
            #pragma unroll
            for (int m = 0; m < 4; ++m) {
                ah[m] = *(const s8v*)(pA[m] + kb * 128);
                al[m] = *(const s8v*)(pA[m] + kb * 128 + 16);
            }
            #pragma unroll
            for (int n = 0; n < 4; ++n) {
                bh[n] = *(const s8v*)(pB[n] + kb * 128);
                bl[n] = *(const s8v*)(pB[n] + kb * 128 + 16);
            }
            #pragma unroll
            for (int m = 0; m < 4; ++m)
                #pragma unroll
                for (int n = 0; n < 4; ++n) {
                    acc[m][n] = __builtin_amdgcn_mfma_f32_16x16x32_bf16(ah[m], bh[n], acc[m][n], 0, 0, 0);
                    acc[m][n] = __builtin_amdgcn_mfma_f32_16x16x32_bf16(ah[m], bl[n], acc[m][n], 0, 0, 0);
                    acc[m][n] = __builtin_amdgcn_mfma_f32_16x16x32_bf16(al[m], bh[n], acc[m][n], 0, 0, 0);
                }
        }
    }

    // Epilogue. D: col = lm -> x2; row = lg*4 + r -> oc within tile.
    const int od = 2 * zb + pd;
    #pragma unroll
    for (int m = 0; m < 4; ++m) {
        const int oc0 = ocb * 128 + wm * 64 + m * 16 + lg * 4;
        const f4v bv4 = *(const f4v*)(bias + oc0);
        const float bvr[4] = {bv4[0], bv4[1], bv4[2], bv4[3]};
        #pragma unroll
        for (int n = 0; n < 4; ++n) {
            const int xh   = (XH == 2) ? (n & 1) : 0;
            const int yloc = (XH == 2) ? (n >> 1) : n;
            const int y2 = yg * (2 * NTY) + wn * NTY + yloc;
            const int oh = 2 * y2 + ph;
            const int ow = 2 * (xh * 16 + lm) + pw;
            if (TOBF16) {
                const size_t spat = ((size_t)od * OUTD + oh) * OUTD + ow;
                unsigned short hq[4], lq[4];
                #pragma unroll
                for (int r = 0; r < 4; ++r) {
                    float v = fmaxf(acc[m][n][r] + bvr[r], 0.0f);
                    bf16split(v, hq[r], lq[r]);
                }
                const size_t bidx = (spat * (OC / 8) + (oc0 >> 3)) * 16 + (oc0 & 7);
                *(ushort4*)(outB + bidx)     = make_ushort4(hq[0], hq[1], hq[2], hq[3]);
                *(ushort4*)(outB + bidx + 8) = make_ushort4(lq[0], lq[1], lq[2], lq[3]);
            } else {
                #pragma unroll
                for (int r = 0; r < 4; ++r) {
                    float v = fmaxf(acc[m][n][r] + bvr[r], 0.0f);
                    const size_t oi = (((size_t)(oc0 + r) * OUTD + od) * OUTD + oh) * OUTD + ow;
                    outF[oi] = v;
                }
            }
        }
    }
}

// ---------------------------------------------------------------------------
// out[i] = bias[i >> VOLSHIFT], float4-wide.
template<int VOLSHIFT>
__global__ __launch_bounds__(256)
void bias_init(const float* __restrict__ bias, float* __restrict__ out, int n)
{
    int i = (blockIdx.x * 256 + threadIdx.x) * 4;
    if (i >= n) return;
    float bv = bias[i >> VOLSHIFT];
    float4 r; r.x = bv; r.y = bv; r.z = bv; r.w = bv;
    *(float4*)&out[i] = r;
}

__global__ __launch_bounds__(256)
void relu_inplace(float* __restrict__ p, int n)
{
    int i = (blockIdx.x * 256 + threadIdx.x) * 4;
    if (i >= n) return;
    float4 a = *(const float4*)&p[i];
    a.x = fmaxf(a.x, 0.0f); a.y = fmaxf(a.y, 0.0f);
    a.z = fmaxf(a.z, 0.0f); a.w = fmaxf(a.w, 0.0f);
    *(float4*)&p[i] = a;
}

// ---------------------------------------------------------------------------
// conv k=4 s=2 p=1 (one batch), fp32 scalar-weight. Unchanged from R5.
template<int IC, int OC, int IND, bool RELU, int ICC, int Q, int KS, bool ATOMIC>
__global__ __launch_bounds__(256)
void conv_sw(const float* __restrict__ in, const float* __restrict__ wT,
             const float* __restrict__ bias, float* __restrict__ out)
{
    constexpr int OUTD = IND / 2;
    constexpr int NTW = OUTD / 8, NTH = OUTD / 8;
    constexpr int ICB = IC / KS;
    __shared__ float sIn[ICC][8][405];

    const int t = threadIdx.x;
    const int bx = blockIdx.x;
    const int twi = bx % NTW;
    const int thi = (bx / NTW) % NTH;
    const int tdi = bx / (NTW * NTH);
    const int ocBase = blockIdx.y * Q;
    const int icStart = blockIdx.z * ICB;

    const int d = t >> 6;
    const int h = (t >> 3) & 7;
    const int w = t & 7;

    float acc[Q];
    #pragma unroll
    for (int j = 0; j < Q; ++j) acc[j] = ATOMIC ? 0.0f : bias[ocBase + j];

    const int id0 = 2 * (tdi * 4) - 1;
    const int ih0 = 2 * (thi * 8) - 1;
    const int iw0 = 2 * (twi * 8) - 1;

    #pragma unroll 1
    for (int ic0 = icStart; ic0 < icStart + ICB; ic0 += ICC) {
        __syncthreads();
        for (int p = t; p < ICC * 3240; p += 256) {
            int icc = p / 3240;
            int r   = p - icc * 3240;
            int li  = r / 324;
            int r2  = r - li * 324;
            int lh  = r2 / 18;
            int lw  = r2 - lh * 18;
            int gd = id0 + li, gh = ih0 + lh, gw = iw0 + lw;
            float v = 0.0f;
            if ((unsigned)gd < (unsigned)IND && (unsigned)gh < (unsigned)IND &&
                (unsigned)gw < (unsigned)IND)
                v = in[((ic0 + icc) * IND + gd) * IND * IND + gh * IND + gw];
            sIn[icc][((li & 1) << 2) | ((lh & 1) << 1) | (lw & 1)]
               [(li >> 1) * 81 + (lh >> 1) * 9 + (lw >> 1)] = v;
        }
        __syncthreads();
        #pragma unroll 1
        for (int icc = 0; icc < ICC; ++icc) {
            const int ic = ic0 + icc;
            #pragma unroll 1
            for (int kd = 0; kd < 4; ++kd) {
                #pragma unroll
                for (int kh = 0; kh < 4; ++kh)
                #pragma unroll
                for (int kw = 0; kw < 4; ++kw) {
                    const float iv = sIn[icc][((kd & 1) << 2) | ((kh & 1) << 1) | (kw & 1)]
                        [(d + (kd >> 1)) * 81 + (h + (kh >> 1)) * 9 + (w + (kw >> 1))];
                    const float* __restrict__ wr =
                        wT + (ic * 64 + (kd * 16 + kh * 4 + kw)) * OC + ocBase;
                    #pragma unroll
                    for (int j = 0; j < Q; ++j) acc[j] = fmaf(iv, wr[j], acc[j]);
                }
            }
        }
    }

    const int od = tdi * 4 + d;
    const int oh = thi * 8 + h;
    const int ow = twi * 8 + w;
    #pragma unroll
    for (int j = 0; j < Q; ++j) {
        const int oi = ((ocBase + j) * OUTD + od) * OUTD * OUTD + oh * OUTD + ow;
        if (ATOMIC) {
            atomicAdd(&out[oi], acc[j]);
        } else {
            float v = acc[j];
            if (RELU) v = fmaxf(v, 0.0f);
            out[oi] = v;
        }
    }
}

// ---------------------------------------------------------------------------
// Fused (deconv3 . conv1x1), fp32, unchanged from R5.
__global__ __launch_bounds__(256)
void deconv_final_sw(const float* __restrict__ in, const float* __restrict__ dwe,
                     const float* __restrict__ beP, float* __restrict__ out)
{
    constexpr int IC = 128, IND = 64, OUTD = 128, ICC = 2;
    __shared__ float sIn[ICC][3240];

    const int t = threadIdx.x;
    const int bx = blockIdx.x;
    const int bw = bx & 3;
    const int bh = (bx >> 2) & 3;
    const int bd = bx >> 4;

    const int td_ = t >> 6;
    const int th_ = (t >> 3) & 7;
    const int tw_ = t & 7;

    const int gd0 = 8 * bd - 1;
    const int gh0 = 16 * bh - 1;
    const int gw0 = 16 * bw - 1;

    float acc[4][4][4];
    #pragma unroll
    for (int a = 0; a < 4; ++a)
        #pragma unroll
        for (int bq = 0; bq < 4; ++bq)
            #pragma unroll
            for (int c = 0; c < 4; ++c) acc[a][bq][c] = 0.0f;

    constexpr int PI[8] = {0,1,1,1,2,2,2,3};
    constexpr int PK[8] = {3,1,2,3,0,1,2,0};
    constexpr int PO[8] = {0,0,1,2,1,2,3,3};

    #pragma unroll 1
    for (int ic0 = 0; ic0 < IC; ic0 += ICC) {
        __syncthreads();
        for (int p = t; p < ICC * 3240; p += 256) {
            int icc = p / 3240;
            int r   = p - icc * 3240;
            int li  = r / 324;
            int r2  = r - li * 324;
            int lh  = r2 / 18;
            int lw  = r2 - lh * 18;
            int gd = gd0 + li, gh = gh0 + lh, gw = gw0 + lw;
            float v = 0.0f;
            if ((unsigned)gd < (unsigned)IND && (unsigned)gh < (unsigned)IND &&
                (unsigned)gw < (unsigned)IND)
                v = in[((ic0 + icc) * IND + gd) * IND * IND + gh * IND + gw];
            sIn[icc][r] = v;
        }
        __syncthreads();
        #pragma unroll 1
        for (int icc = 0; icc < ICC; ++icc) {
            const int ic = ic0 + icc;
            const float* __restrict__ wv = dwe + ic * 64;
            float riv[4][4][4];
            #pragma unroll
            for (int id = 0; id < 4; ++id)
                #pragma unroll
                for (int ih = 0; ih < 4; ++ih) {
                    const int off = (2 * td_ + id) * 324 + (2 * th_ + ih) * 18 + 2 * tw_;
                    const float2 r01 = *(const float2*)&sIn[icc][off];
                    const float2 r23 = *(const float2*)&sIn[icc][off + 2];
                    riv[id][ih][0] = r01.x; riv[id][ih][1] = r01.y;
                    riv[id][ih][2] = r23.x; riv[id][ih][3] = r23.y;
                }
            #pragma unroll
            for (int a = 0; a < 8; ++a)
                #pragma unroll
                for (int bq = 0; bq < 8; ++bq)
                    #pragma unroll
                    for (int c = 0; c < 8; ++c)
                        acc[PO[a]][PO[bq]][PO[c]] =
                            fmaf(riv[PI[a]][PI[bq]][PI[c]],
                                 wv[PK[a] * 16 + PK[bq] * 4 + PK[c]],
                                 acc[PO[a]][PO[bq]][PO[c]]);
        }
    }

    const float be = *beP;
    #pragma unroll
    for (int a = 0; a < 4; ++a)
        #pragma unroll
        for (int bq = 0; bq < 4; ++bq) {
            const int od = 16 * bd + 4 * td_ + a;
            const int oh = 32 * bh + 4 * th_ + bq;
            const int ow = 32 * bw + 4 * tw_;
            float* orow = &out[(od * OUTD + oh) * OUTD + ow];
            orow[0] = acc[a][bq][0] + be;
            orow[1] = acc[a][bq][1] + be;
            orow[2] = acc[a][bq][2] + be;
            orow[3] = acc[a][bq][3] + be;
        }
}

// ---------------------------------------------------------------------------
__global__ void esq_kernel(const float* __restrict__ emb, float* __restrict__ eSq)
{
    int k = blockIdx.x * 256 + threadIdx.x;
    if (k < 512) {
        float s = 0.0f;
        #pragma unroll
        for (int e = 0; e < 64; ++e) { float v = emb[k * 64 + e]; s += v * v; }
        eSq[k] = s;
    }
}

__global__ void fold_kernel(const float* __restrict__ dw3, const float* __restrict__ wo,
                            const float* __restrict__ db3, const float* __restrict__ bo,
                            float* __restrict__ dwe, float* __restrict__ beP)
{
    int idx = blockIdx.x * 256 + threadIdx.x;
    int ic = idx >> 6, tap = idx & 63;
    float s = 0.0f;
    for (int c = 0; c < 128; ++c) s += dw3[(ic * 128 + c) * 64 + tap] * wo[c];
    dwe[idx] = s;
    if (idx == 0) {
        float bb = bo[0];
        for (int c = 0; c < 128; ++c) bb += wo[c] * db3[c];
        *beP = bb;
    }
}

__global__ void zero_kernel(float* __restrict__ la, float* __restrict__ zpage)
{
    zpage[threadIdx.x] = 0.0f;          // 256 floats = 1 KB zero page
    if (threadIdx.x == 0) la[0] = 0.0f;
}

// One batch VQ. Writes q as channels-last bf16 hi/lo (interleaved per 8-ic group).
__global__ __launch_bounds__(256)
void vq_kernel(const float* __restrict__ h3, const float* __restrict__ emb,
               const float* __restrict__ eSq, unsigned short* __restrict__ qx,
               float* __restrict__ lossAcc)
{
    __shared__ float sDist[4][64];
    __shared__ int   sIdx[4][64];
    const int t = threadIdx.x;
    const int vec = blockIdx.x * 64 + (t & 63);
    const int kq = t >> 6;
    const int cg = vec & 3;
    const int spat = vec >> 2;
    const int base = (cg * 64) * 4096 + spat;

    float v[64];
    #pragma unroll
    for (int e = 0; e < 64; ++e) v[e] = h3[base + e * 4096];

    float fSq = 0.0f;
    #pragma unroll
    for (int e = 0; e < 64; ++e) fSq += v[e] * v[e];

    float best = 1e30f; int bidx = 0;
    const int k0 = __builtin_amdgcn_readfirstlane(kq) * 128;
    for (int kk = 0; kk < 128; ++kk) {
        const int k = k0 + kk;
        const float* er = emb + k * 64;
        float d0 = 0, d1 = 0, d2 = 0, d3 = 0;
        #pragma unroll
        for (int e = 0; e < 64; e += 4) {
            d0 += v[e]     * er[e];
            d1 += v[e + 1] * er[e + 1];
            d2 += v[e + 2] * er[e + 2];
            d3 += v[e + 3] * er[e + 3];
        }
        const float s1 = fSq + eSq[k];
        const float dist = s1 - 2.0f * ((d0 + d1) + (d2 + d3));
        if (dist < best) { best = dist; bidx = k; }
    }
    sDist[kq][t & 63] = best;
    sIdx[kq][t & 63]  = bidx;
    __syncthreads();
    if (t < 64) {
        float bd = sDist[0][t]; int bi = sIdx[0][t];
        #pragma unroll
        for (int j = 1; j < 4; ++j) {
            float d = sDist[j][t]; int i2 = sIdx[j][t];
            if (d < bd || (d == bd && i2 < bi)) { bd = d; bi = i2; }
        }
        const float* er = emb + bi * 64;
        float ls = 0.0f;
        #pragma unroll
        for (int e = 0; e < 64; ++e) {
            float qe = er[e];
            int ic = cg * 64 + e;
            unsigned short hh, ll;
            bf16split(qe, hh, ll);
            size_t qi = ((size_t)spat * 32 + (ic >> 3)) * 16 + (ic & 7);
            qx[qi]     = hh;
            qx[qi + 8] = ll;
            float df = qe - v[e];
            ls += df * df;
        }
        #pragma unroll
        for (int off = 32; off > 0; off >>= 1) ls += __shfl_down(ls, off);
        if (t == 0) atomicAdd(lossAcc, ls);
    }
}

__global__ void loss_final(const float* __restrict__ lossAcc, float* __restrict__ out)
{
    out[0] = 1.25f * lossAcc[0] / 2097152.0f;
}

// ---------------------------------------------------------------------------
extern "C" void kernel_launch(void* const* d_in, const int* in_sizes, int n_in,
                              void* d_out, int out_size, void* d_ws, size_t ws_size,
                              hipStream_t stream)
{
    (void)in_sizes; (void)n_in; (void)out_size; (void)ws_size;
    const float* x   = (const float*)d_in[0];
    const float* w1  = (const float*)d_in[1];
    const float* b1  = (const float*)d_in[2];
    const float* w2  = (const float*)d_in[3];
    const float* b2  = (const float*)d_in[4];
    const float* w3  = (const float*)d_in[5];
    const float* b3  = (const float*)d_in[6];
    const float* dw1 = (const float*)d_in[7];
    const float* db1 = (const float*)d_in[8];
    const float* dw2 = (const float*)d_in[9];
    const float* db2 = (const float*)d_in[10];
    const float* dw3 = (const float*)d_in[11];
    const float* db3 = (const float*)d_in[12];
    const float* wo  = (const float*)d_in[13];
    const float* bo  = (const float*)d_in[14];
    const float* emb = (const float*)d_in[15];

    // Workspace (floats). Footprint ~226.6 MB (same as R5-passing layout).
    float* ws   = (float*)d_ws;
    float* A    = ws;                          // 33,554,432  h1 / r2
    float* Bb   = A + 33554432;                //  8,388,608  h2; aliased r1x (bf16 cl)
    float* C    = Bb + 8388608;                //  1,048,576  h3
    float* Dq   = C + 1048576;                 //  1,048,576  qx (bf16 cl)
    float* wT1  = Dq + 1048576;                //      8,192
    float* wT2  = wT1 + 8192;                  //  2,097,152
    float* wT3  = wT2 + 2097152;               //  4,194,304
    float* Wm1f = wT3 + 4194304;               //  4,194,304  (16.78 MB Wm1x)
    float* Wm2f = Wm1f + 4194304;              //  2,097,152  ( 8.39 MB Wm2x)
    float* dwe  = Wm2f + 2097152;              //      8,192
    float* eSq  = dwe + 8192;                  //        512
    float* lossAcc = eSq + 512;                //          1
    float* beP  = lossAcc + 1;                 //          1
    float* zpage = lossAcc + 3;                //        256 (16B-aligned)

    unsigned short* qx   = (unsigned short*)Dq;
    unsigned short* r1x  = (unsigned short*)Bb;
    unsigned short* Wm1x = (unsigned short*)Wm1f;
    unsigned short* Wm2x = (unsigned short*)Wm2f;

    float* outLoss = (float*)d_out;
    float* outR    = (float*)d_out + 1;

    zero_kernel<<<dim3(1), 256, 0, stream>>>(lossAcc, zpage);

    // weight prep (per call; ws re-poisoned by harness)
    repack_w<1,   128, false><<<dim3(32),    256, 0, stream>>>(w1,  wT1);
    repack_w<128, 256, false><<<dim3(8192),  256, 0, stream>>>(w2,  wT2);
    repack_w<256, 256, false><<<dim3(16384), 256, 0, stream>>>(w3,  wT3);
    repack_mfma<256, 256><<<dim3(16384), 256, 0, stream>>>(dw1, Wm1x);
    repack_mfma<256, 128><<<dim3(8192),  256, 0, stream>>>(dw2, Wm2x);
    fold_kernel<<<dim3(32), 256, 0, stream>>>(dw3, wo, db3, bo, dwe, beP);
    esq_kernel<<<dim3(2), 256, 0, stream>>>(emb, eSq);

    for (int b = 0; b < 2; ++b) {
        const float* xb = x + (size_t)b * 2097152;
        float* rb = outR + (size_t)b * 2097152;

        // encoder (fp32, unchanged)
        conv_sw<1, 128, 128, true, 1, 64, 1, false><<<dim3(1024, 2, 1), 256, 0, stream>>>(xb, wT1, b1, A);

        bias_init<15><<<dim3(8192), 256, 0, stream>>>(b2, Bb, 8388608);
        conv_sw<128, 256, 64, false, 2, 64, 4, true><<<dim3(128, 4, 4), 256, 0, stream>>>(A, wT2, b2, Bb);
        relu_inplace<<<dim3(8192), 256, 0, stream>>>(Bb, 8388608);

        bias_init<12><<<dim3(1024), 256, 0, stream>>>(b3, C, 1048576);
        conv_sw<256, 256, 32, false, 2, 32, 8, true><<<dim3(16, 8, 8), 256, 0, stream>>>(Bb, wT3, b3, C);

        // VQ -> qx (channels-last bf16 hi/lo) + loss
        vq_kernel<<<dim3(256), 256, 0, stream>>>(C, emb, eSq, qx, lossAcc);

        // decoder (MFMA split-bf16)
        deconv_mfma<256, 256, 16, true ><<<dim3(32, 8, 2),  256, 0, stream>>>(qx,  Wm1x, db1, nullptr, r1x, zpage);
        deconv_mfma<256, 128, 32, false><<<dim3(256, 8, 1), 256, 0, stream>>>(r1x, Wm2x, db2, A, nullptr, zpage);

        deconv_final_sw<<<dim3(128), 256, 0, stream>>>(A, dwe, beP, rb);
    }

    loss_final<<<dim3(1), 1, 0, stream>>>(lossAcc, outLoss);
}

// Round 7
// 6703.784 us; speedup vs baseline: 2.7383x; 1.4338x over previous
//
#include <hip/hip_runtime.h>

// VQ-VAE fwd on MI355X.
//  - R7: encoder conv2/conv3 -> MFMA split-bf16 implicit GEMM (same structure
//    as the R6 decoder, which passed with absmax unchanged). conv1 stays fp32
//    scalar-weight but emits channels-last bf16 hi/lo. h3 becomes channels-last
//    fp32 (VQ loads turn into coalesced float4s). conv3 tap-split 8 ways into
//    fp32 partials + deterministic reduce (occupancy).
//  - deconv3 folded into 1x1 output conv (fused fp32 final kernel).
//  - split-bf16: x = xh + xl, w = wh + wl, keep 3 terms (drop wl*xl ~ 2^-18).

typedef short  s8v  __attribute__((ext_vector_type(8)));
typedef float  f4v  __attribute__((ext_vector_type(4)));

__device__ inline void bf16split(float v, unsigned short& h, unsigned short& l)
{
    unsigned u = __float_as_uint(v);
    unsigned hr = (u + 0x7FFFu + ((u >> 16) & 1u)) >> 16;   // RNE
    h = (unsigned short)hr;
    float hf = __uint_as_float(hr << 16);
    float r = v - hf;
    unsigned u2 = __float_as_uint(r);
    l = (unsigned short)((u2 + 0x7FFFu + ((u2 >> 16) & 1u)) >> 16);
}

// ---------------------------------------------------------------------------
// fp32 weight repack (conv1 only): wT[(ic*64 + tap)*OC + oc].
template<int IC, int OC, bool TR>
__global__ __launch_bounds__(256)
void repack_w(const float* __restrict__ src, float* __restrict__ dst)
{
    int idx = blockIdx.x * 256 + threadIdx.x;
    if (idx >= IC * OC * 64) return;
    int oc  = idx % OC;
    int rem = idx / OC;
    int tap = rem % 64;
    int ic  = rem / 64;
    float v = TR ? src[(ic * OC + oc) * 64 + tap]
                 : src[(oc * IC + ic) * 64 + tap];
    dst[idx] = v;
}

// ---------------------------------------------------------------------------
// MFMA weight repack, deconv (IC,OC,4,4,4): [cs=(class*8+sel)][oc][icg][hi8|lo8].
template<int IC, int OC>
__global__ __launch_bounds__(256)
void repack_mfma(const float* __restrict__ src, unsigned short* __restrict__ dst)
{
    int idx = blockIdx.x * 256 + threadIdx.x;
    if (idx >= 64 * OC * IC) return;
    int ic  = idx % IC;
    int rem = idx / IC;
    int oc  = rem % OC;
    int cs  = rem / OC;
    int c = cs >> 3, s = cs & 7;
    int pd = (c >> 2) & 1, ph = (c >> 1) & 1, pw = c & 1;
    int sd = (s >> 2) & 1, sh = (s >> 1) & 1, sw = s & 1;
    int td = (sd ? 1 : 3) - pd;
    int th = (sh ? 1 : 3) - ph;
    int tw = (sw ? 1 : 3) - pw;
    int tap = td * 16 + th * 4 + tw;
    float w = src[(ic * OC + oc) * 64 + tap];
    unsigned short h, l;
    bf16split(w, h, l);
    size_t base = ((size_t)(cs * OC + oc) * (IC / 8) + (ic >> 3)) * 16 + (ic & 7);
    dst[base]     = h;
    dst[base + 8] = l;
}

// MFMA weight repack, conv (OC,IC,4,4,4): [tap][oc][icg][hi8|lo8].
template<int IC, int OC>
__global__ __launch_bounds__(256)
void repack_cmfma(const float* __restrict__ src, unsigned short* __restrict__ dst)
{
    int idx = blockIdx.x * 256 + threadIdx.x;
    if (idx >= 64 * OC * IC) return;
    int ic  = idx % IC;
    int rem = idx / IC;
    int oc  = rem % OC;
    int tap = rem / OC;
    float w = src[(oc * IC + ic) * 64 + tap];
    unsigned short h, l;
    bf16split(w, h, l);
    size_t base = ((size_t)(tap * OC + oc) * (IC / 8) + (ic >> 3)) * 16 + (ic & 7);
    dst[base]     = h;
    dst[base + 8] = l;
}

// ---------------------------------------------------------------------------
// MFMA conv k4s2p1, split-bf16. Block: 128oc x 128vox (4 waves = 2wm x 2wn),
// wave: 4 M x 4 N tiles of mfma_f32_16x16x32_bf16. K = taps x IC.
// inx: channels-last bf16 [vox][icg][hi8|lo8]. TAPSPLIT: blockIdx.y = group of 8
// taps, raw fp32 cl partials to outF + y*OUTD^3*OC (bias in reduce). Else all 64
// taps, bias+relu+bf16-cl to outB.
template<int IC, int OC, int IND, bool TAPSPLIT, bool TOBF16>
__global__ __launch_bounds__(256, 2)
void conv_mfma(const unsigned short* __restrict__ inx,
               const unsigned short* __restrict__ wx,
               const float* __restrict__ bias,
               float* __restrict__ outF, unsigned short* __restrict__ outB,
               const float* __restrict__ zpage)
{
    constexpr int OUTD = IND / 2;
    constexpr int XH  = OUTD / 16;      // x halves (2 for OUTD=32, 1 for 16)
    constexpr int NTY = 4 / XH;
    constexpr int YG  = OUTD / (2 * NTY);

    const int t  = threadIdx.x;
    const int l  = t & 63;
    const int wid = t >> 6;
    const int wm = wid >> 1;
    const int wn = wid & 1;
    const int lm = l & 15;
    const int lg = l >> 4;

    const int yg  = blockIdx.x % YG;
    const int zb  = blockIdx.x / YG;    // od
    const int ocb = blockIdx.z;
    const int tb  = TAPSPLIT ? blockIdx.y * 8 : 0;
    const int tn  = TAPSPLIT ? 8 : 64;

    const char* __restrict__ ibase = (const char*)inx;
    const char* __restrict__ wbase = (const char*)wx;
    const char* __restrict__ zb_c  = (const char*)zpage;

    f4v acc[4][4];
    #pragma unroll
    for (int m = 0; m < 4; ++m)
        #pragma unroll
        for (int n = 0; n < 4; ++n)
            acc[m][n] = (f4v){0.f, 0.f, 0.f, 0.f};

    #pragma unroll 1
    for (int tt = 0; tt < tn; ++tt) {
        const int tap = tb + tt;
        const int kd = tap >> 4, kh = (tap >> 2) & 3, kw = tap & 3;
        const int iz = 2 * zb + kd - 1;
        const bool zbad = (unsigned)iz >= (unsigned)IND;

        const char* pA[4];
        #pragma unroll
        for (int m = 0; m < 4; ++m) {
            const int oc = ocb * 128 + wm * 64 + m * 16 + lm;
            pA[m] = wbase + ((size_t)(tap * OC + oc) * (IC / 8) + lg) * 32;
        }
        const char* pB[4];
        #pragma unroll
        for (int n = 0; n < 4; ++n) {
            const int xh   = (XH == 2) ? (n & 1) : 0;
            const int yloc = (XH == 2) ? (n >> 1) : n;
            const int oh = yg * (2 * NTY) + wn * NTY + yloc;
            const int iy = 2 * oh + kh - 1;
            const int ow = xh * 16 + lm;
            const int ix = 2 * ow + kw - 1;
            const bool bad = zbad || ((unsigned)iy >= (unsigned)IND)
                                  || ((unsigned)ix >= (unsigned)IND);
            const char* p = ibase +
                ((size_t)((iz * IND + iy) * IND + ix) * (IC / 8) + lg) * 32;
            pB[n] = bad ? zb_c : p;
        }

        #pragma unroll 2
        for (int kb = 0; kb < IC / 32; ++kb) {
            s8v ah[4], al[4], bh[4], bl[4];
            #pragma unroll
            for (int m = 0; m < 4; ++m) {
                ah[m] = *(const s8v*)(pA[m] + kb * 128);
                al[m] = *(const s8v*)(pA[m] + kb * 128 + 16);
            }
            #pragma unroll
            for (int n = 0; n < 4; ++n) {
                bh[n] = *(const s8v*)(pB[n] + kb * 128);
                bl[n] = *(const s8v*)(pB[n] + kb * 128 + 16);
            }
            #pragma unroll
            for (int m = 0; m < 4; ++m)
                #pragma unroll
                for (int n = 0; n < 4; ++n) {
                    acc[m][n] = __builtin_amdgcn_mfma_f32_16x16x32_bf16(ah[m], bh[n], acc[m][n], 0, 0, 0);
                    acc[m][n] = __builtin_amdgcn_mfma_f32_16x16x32_bf16(ah[m], bl[n], acc[m][n], 0, 0, 0);
                    acc[m][n] = __builtin_amdgcn_mfma_f32_16x16x32_bf16(al[m], bh[n], acc[m][n], 0, 0, 0);
                }
        }
    }

    const int od = zb;
    #pragma unroll
    for (int m = 0; m < 4; ++m) {
        const int oc0 = ocb * 128 + wm * 64 + m * 16 + lg * 4;
        float bvr[4] = {0.f, 0.f, 0.f, 0.f};
        if (TOBF16) {
            const f4v bv4 = *(const f4v*)(bias + oc0);
            bvr[0] = bv4[0]; bvr[1] = bv4[1]; bvr[2] = bv4[2]; bvr[3] = bv4[3];
        }
        #pragma unroll
        for (int n = 0; n < 4; ++n) {
            const int xh   = (XH == 2) ? (n & 1) : 0;
            const int yloc = (XH == 2) ? (n >> 1) : n;
            const int oh = yg * (2 * NTY) + wn * NTY + yloc;
            const int ow = xh * 16 + lm;
            const size_t spat = ((size_t)od * OUTD + oh) * OUTD + ow;
            if (TOBF16) {
                unsigned short hq[4], lq[4];
                #pragma unroll
                for (int r = 0; r < 4; ++r) {
                    float v = fmaxf(acc[m][n][r] + bvr[r], 0.0f);
                    bf16split(v, hq[r], lq[r]);
                }
                const size_t bidx = (spat * (OC / 8) + (oc0 >> 3)) * 16 + (oc0 & 7);
                *(ushort4*)(outB + bidx)     = make_ushort4(hq[0], hq[1], hq[2], hq[3]);
                *(ushort4*)(outB + bidx + 8) = make_ushort4(lq[0], lq[1], lq[2], lq[3]);
            } else {
                float* __restrict__ o2 = outF + (size_t)blockIdx.y * (OUTD * OUTD * OUTD * OC);
                float4 vst;
                vst.x = acc[m][n][0]; vst.y = acc[m][n][1];
                vst.z = acc[m][n][2]; vst.w = acc[m][n][3];
                *(float4*)&o2[spat * OC + oc0] = vst;
            }
        }
    }
}

// ---------------------------------------------------------------------------
// MFMA deconv k4s2p1 (unchanged from R6, passing).
template<int IC, int OC, int IND, bool TOBF16>
__global__ __launch_bounds__(256, 2)
void deconv_mfma(const unsigned short* __restrict__ inx,
                 const unsigned short* __restrict__ wx,
                 const float* __restrict__ bias,
                 float* __restrict__ outF, unsigned short* __restrict__ outB,
                 const float* __restrict__ zpage)
{
    constexpr int OUTD = IND * 2;
    constexpr int XH  = IND / 16;
    constexpr int NTY = 4 / XH;
    constexpr int YG  = IND / (2 * NTY);

    const int t  = threadIdx.x;
    const int l  = t & 63;
    const int wid = t >> 6;
    const int wm = wid >> 1;
    const int wn = wid & 1;
    const int lm = l & 15;
    const int lg = l >> 4;

    const int yg  = blockIdx.x % YG;
    const int zb  = blockIdx.x / YG;
    const int cls = blockIdx.y;
    const int ocb = blockIdx.z;

    const int pd = (cls >> 2) & 1, ph = (cls >> 1) & 1, pw = cls & 1;

    const char* __restrict__ ibase = (const char*)inx;
    const char* __restrict__ wbase = (const char*)wx;
    const char* __restrict__ zb_c  = (const char*)zpage;

    f4v acc[4][4];
    #pragma unroll
    for (int m = 0; m < 4; ++m)
        #pragma unroll
        for (int n = 0; n < 4; ++n)
            acc[m][n] = (f4v){0.f, 0.f, 0.f, 0.f};

    #pragma unroll 1
    for (int s = 0; s < 8; ++s) {
        const int sd = (s >> 2) & 1, sh = (s >> 1) & 1, sw = s & 1;
        const int iz = zb + pd + sd - 1;
        const bool zbad = (unsigned)iz >= (unsigned)IND;

        const char* pA[4];
        #pragma unroll
        for (int m = 0; m < 4; ++m) {
            const int oc = ocb * 128 + wm * 64 + m * 16 + lm;
            pA[m] = wbase + ((size_t)((cls * 8 + s) * OC + oc) * (IC / 8) + lg) * 32;
        }
        const char* pB[4];
        #pragma unroll
        for (int n = 0; n < 4; ++n) {
            const int xh   = (XH == 2) ? (n & 1) : 0;
            const int yloc = (XH == 2) ? (n >> 1) : n;
            const int y2 = yg * (2 * NTY) + wn * NTY + yloc;
            const int iy = y2 + ph + sh - 1;
            const int x2 = xh * 16 + lm;
            const int ix = x2 + pw + sw - 1;
            const bool bad = zbad || ((unsigned)iy >= (unsigned)IND)
                                  || ((unsigned)ix >= (unsigned)IND);
            const char* p = ibase +
                ((size_t)((iz * IND + iy) * IND + ix) * (IC / 8) + lg) * 32;
            pB[n] = bad ? zb_c : p;
        }

        #pragma unroll 2
        for (int kb = 0; kb < IC / 32; ++kb) {
            s8v ah[4], al[4], bh[4], bl[4];
            #pragma unroll
            for (int m = 0; m < 4; ++m) {
                ah[m] = *(const s8v*)(pA[m] + kb * 128);
                al[m] = *(const s8v*)(pA[m] + kb * 128 + 16);
            }
            #pragma unroll
            for (int n = 0; n < 4; ++n) {
                bh[n] = *(const s8v*)(pB[n] + kb * 128);
                bl[n] = *(const s8v*)(pB[n] + kb * 128 + 16);
            }
            #pragma unroll
            for (int m = 0; m < 4; ++m)
                #pragma unroll
                for (int n = 0; n < 4; ++n) {
                    acc[m][n] = __builtin_amdgcn_mfma_f32_16x16x32_bf16(ah[m], bh[n], acc[m][n], 0, 0, 0);
                    acc[m][n] = __builtin_amdgcn_mfma_f32_16x16x32_bf16(ah[m], bl[n], acc[m][n], 0, 0, 0);
                    acc[m][n] = __builtin_amdgcn_mfma_f32_16x16x32_bf16(al[m], bh[n], acc[m][n], 0, 0, 0);
                }
        }
    }

    const int od = 2 * zb + pd;
    #pragma unroll
    for (int m = 0; m < 4; ++m) {
        const int oc0 = ocb * 128 + wm * 64 + m * 16 + lg * 4;
        const f4v bv4 = *(const f4v*)(bias + oc0);
        const float bvr[4] = {bv4[0], bv4[1], bv4[2], bv4[3]};
        #pragma unroll
        for (int n = 0; n < 4; ++n) {
            const int xh   = (XH == 2) ? (n & 1) : 0;
            const int yloc = (XH == 2) ? (n >> 1) : n;
            const int y2 = yg * (2 * NTY) + wn * NTY + yloc;
            const int oh = 2 * y2 + ph;
            const int ow = 2 * (xh * 16 + lm) + pw;
            if (TOBF16) {
                const size_t spat = ((size_t)od * OUTD + oh) * OUTD + ow;
                unsigned short hq[4], lq[4];
                #pragma unroll
                for (int r = 0; r < 4; ++r) {
                    float v = fmaxf(acc[m][n][r] + bvr[r], 0.0f);
                    bf16split(v, hq[r], lq[r]);
                }
                const size_t bidx = (spat * (OC / 8) + (oc0 >> 3)) * 16 + (oc0 & 7);
                *(ushort4*)(outB + bidx)     = make_ushort4(hq[0], hq[1], hq[2], hq[3]);
                *(ushort4*)(outB + bidx + 8) = make_ushort4(lq[0], lq[1], lq[2], lq[3]);
            } else {
                #pragma unroll
                for (int r = 0; r < 4; ++r) {
                    float v = fmaxf(acc[m][n][r] + bvr[r], 0.0f);
                    const size_t oi = (((size_t)(oc0 + r) * OUTD + od) * OUTD + oh) * OUTD + ow;
                    outF[oi] = v;
                }
            }
        }
    }
}

// ---------------------------------------------------------------------------
// conv1: fp32 scalar-weight (IC=1), emits channels-last bf16 hi/lo.
template<int IC, int OC, int IND, bool RELU, int ICC, int Q>
__global__ __launch_bounds__(256)
void conv_sw_cl(const float* __restrict__ in, const float* __restrict__ wT,
                const float* __restrict__ bias, unsigned short* __restrict__ outB)
{
    constexpr int OUTD = IND / 2;
    constexpr int NTW = OUTD / 8, NTH = OUTD / 8;
    __shared__ float sIn[ICC][8][405];

    const int t = threadIdx.x;
    const int bx = blockIdx.x;
    const int twi = bx % NTW;
    const int thi = (bx / NTW) % NTH;
    const int tdi = bx / (NTW * NTH);
    const int ocBase = blockIdx.y * Q;

    const int d = t >> 6;
    const int h = (t >> 3) & 7;
    const int w = t & 7;

    float acc[Q];
    #pragma unroll
    for (int j = 0; j < Q; ++j) acc[j] = bias[ocBase + j];

    const int id0 = 2 * (tdi * 4) - 1;
    const int ih0 = 2 * (thi * 8) - 1;
    const int iw0 = 2 * (twi * 8) - 1;

    #pragma unroll 1
    for (int ic0 = 0; ic0 < IC; ic0 += ICC) {
        __syncthreads();
        for (int p = t; p < ICC * 3240; p += 256) {
            int icc = p / 3240;
            int r   = p - icc * 3240;
            int li  = r / 324;
            int r2  = r - li * 324;
            int lh  = r2 / 18;
            int lw  = r2 - lh * 18;
            int gd = id0 + li, gh = ih0 + lh, gw = iw0 + lw;
            float v = 0.0f;
            if ((unsigned)gd < (unsigned)IND && (unsigned)gh < (unsigned)IND &&
                (unsigned)gw < (unsigned)IND)
                v = in[((ic0 + icc) * IND + gd) * IND * IND + gh * IND + gw];
            sIn[icc][((li & 1) << 2) | ((lh & 1) << 1) | (lw & 1)]
               [(li >> 1) * 81 + (lh >> 1) * 9 + (lw >> 1)] = v;
        }
        __syncthreads();
        #pragma unroll 1
        for (int icc = 0; icc < ICC; ++icc) {
            const int ic = ic0 + icc;
            #pragma unroll 1
            for (int kd = 0; kd < 4; ++kd) {
                #pragma unroll
                for (int kh = 0; kh < 4; ++kh)
                #pragma unroll
                for (int kw = 0; kw < 4; ++kw) {
                    const float iv = sIn[icc][((kd & 1) << 2) | ((kh & 1) << 1) | (kw & 1)]
                        [(d + (kd >> 1)) * 81 + (h + (kh >> 1)) * 9 + (w + (kw >> 1))];
                    const float* __restrict__ wr =
                        wT + (ic * 64 + (kd * 16 + kh * 4 + kw)) * OC + ocBase;
                    #pragma unroll
                    for (int j = 0; j < Q; ++j) acc[j] = fmaf(iv, wr[j], acc[j]);
                }
            }
        }
    }

    const int od = tdi * 4 + d;
    const int oh = thi * 8 + h;
    const int ow = twi * 8 + w;
    const size_t spat = ((size_t)od * OUTD + oh) * OUTD + ow;
    #pragma unroll
    for (int g = 0; g < Q / 8; ++g) {
        const int oc0 = ocBase + g * 8;
        unsigned short hq[8], lq[8];
        #pragma unroll
        for (int j = 0; j < 8; ++j) {
            float v = acc[g * 8 + j];
            if (RELU) v = fmaxf(v, 0.0f);
            bf16split(v, hq[j], lq[j]);
        }
        const size_t bidx = (spat * (OC / 8) + (oc0 >> 3)) * 16;
        *(ushort4*)(outB + bidx)      = make_ushort4(hq[0], hq[1], hq[2], hq[3]);
        *(ushort4*)(outB + bidx + 4)  = make_ushort4(hq[4], hq[5], hq[6], hq[7]);
        *(ushort4*)(outB + bidx + 8)  = make_ushort4(lq[0], lq[1], lq[2], lq[3]);
        *(ushort4*)(outB + bidx + 12) = make_ushort4(lq[4], lq[5], lq[6], lq[7]);
    }
}

// ---------------------------------------------------------------------------
// out[i] = sum_{z<8} p[z*1048576 + i] + bias[i & 255]   (channels-last, OC=256)
__global__ __launch_bounds__(256)
void reduce8_bias_cl(const float* __restrict__ p, const float* __restrict__ bias,
                     float* __restrict__ out)
{
    int i = (blockIdx.x * 256 + threadIdx.x) * 4;
    float4 s = *(const float4*)&p[i];
    #pragma unroll
    for (int z = 1; z < 8; ++z) {
        float4 a = *(const float4*)&p[z * 1048576 + i];
        s.x += a.x; s.y += a.y; s.z += a.z; s.w += a.w;
    }
    float4 bv = *(const float4*)&bias[i & 255];
    s.x += bv.x; s.y += bv.y; s.z += bv.z; s.w += bv.w;
    *(float4*)&out[i] = s;
}

// ---------------------------------------------------------------------------
// Fused (deconv3 . conv1x1), fp32, unchanged.
__global__ __launch_bounds__(256)
void deconv_final_sw(const float* __restrict__ in, const float* __restrict__ dwe,
                     const float* __restrict__ beP, float* __restrict__ out)
{
    constexpr int IC = 128, IND = 64, OUTD = 128, ICC = 2;
    __shared__ float sIn[ICC][3240];

    const int t = threadIdx.x;
    const int bx = blockIdx.x;
    const int bw = bx & 3;
    const int bh = (bx >> 2) & 3;
    const int bd = bx >> 4;

    const int td_ = t >> 6;
    const int th_ = (t >> 3) & 7;
    const int tw_ = t & 7;

    const int gd0 = 8 * bd - 1;
    const int gh0 = 16 * bh - 1;
    const int gw0 = 16 * bw - 1;

    float acc[4][4][4];
    #pragma unroll
    for (int a = 0; a < 4; ++a)
        #pragma unroll
        for (int bq = 0; bq < 4; ++bq)
            #pragma unroll
            for (int c = 0; c < 4; ++c) acc[a][bq][c] = 0.0f;

    constexpr int PI[8] = {0,1,1,1,2,2,2,3};
    constexpr int PK[8] = {3,1,2,3,0,1,2,0};
    constexpr int PO[8] = {0,0,1,2,1,2,3,3};

    #pragma unroll 1
    for (int ic0 = 0; ic0 < IC; ic0 += ICC) {
        __syncthreads();
        for (int p = t; p < ICC * 3240; p += 256) {
            int icc = p / 3240;
            int r   = p - icc * 3240;
            int li  = r / 324;
            int r2  = r - li * 324;
            int lh  = r2 / 18;
            int lw  = r2 - lh * 18;
            int gd = gd0 + li, gh = gh0 + lh, gw = gw0 + lw;
            float v = 0.0f;
            if ((unsigned)gd < (unsigned)IND && (unsigned)gh < (unsigned)IND &&
                (unsigned)gw < (unsigned)IND)
                v = in[((ic0 + icc) * IND + gd) * IND * IND + gh * IND + gw];
            sIn[icc][r] = v;
        }
        __syncthreads();
        #pragma unroll 1
        for (int icc = 0; icc < ICC; ++icc) {
            const int ic = ic0 + icc;
            const float* __restrict__ wv = dwe + ic * 64;
            float riv[4][4][4];
            #pragma unroll
            for (int id = 0; id < 4; ++id)
                #pragma unroll
                for (int ih = 0; ih < 4; ++ih) {
                    const int off = (2 * td_ + id) * 324 + (2 * th_ + ih) * 18 + 2 * tw_;
                    const float2 r01 = *(const float2*)&sIn[icc][off];
                    const float2 r23 = *(const float2*)&sIn[icc][off + 2];
                    riv[id][ih][0] = r01.x; riv[id][ih][1] = r01.y;
                    riv[id][ih][2] = r23.x; riv[id][ih][3] = r23.y;
                }
            #pragma unroll
            for (int a = 0; a < 8; ++a)
                #pragma unroll
                for (int bq = 0; bq < 8; ++bq)
                    #pragma unroll
                    for (int c = 0; c < 8; ++c)
                        acc[PO[a]][PO[bq]][PO[c]] =
                            fmaf(riv[PI[a]][PI[bq]][PI[c]],
                                 wv[PK[a] * 16 + PK[bq] * 4 + PK[c]],
                                 acc[PO[a]][PO[bq]][PO[c]]);
        }
    }

    const float be = *beP;
    #pragma unroll
    for (int a = 0; a < 4; ++a)
        #pragma unroll
        for (int bq = 0; bq < 4; ++bq) {
            const int od = 16 * bd + 4 * td_ + a;
            const int oh = 32 * bh + 4 * th_ + bq;
            const int ow = 32 * bw + 4 * tw_;
            float* orow = &out[(od * OUTD + oh) * OUTD + ow];
            orow[0] = acc[a][bq][0] + be;
            orow[1] = acc[a][bq][1] + be;
            orow[2] = acc[a][bq][2] + be;
            orow[3] = acc[a][bq][3] + be;
        }
}

// ---------------------------------------------------------------------------
__global__ void esq_kernel(const float* __restrict__ emb, float* __restrict__ eSq)
{
    int k = blockIdx.x * 256 + threadIdx.x;
    if (k < 512) {
        float s = 0.0f;
        #pragma unroll
        for (int e = 0; e < 64; ++e) { float v = emb[k * 64 + e]; s += v * v; }
        eSq[k] = s;
    }
}

__global__ void fold_kernel(const float* __restrict__ dw3, const float* __restrict__ wo,
                            const float* __restrict__ db3, const float* __restrict__ bo,
                            float* __restrict__ dwe, float* __restrict__ beP)
{
    int idx = blockIdx.x * 256 + threadIdx.x;
    int ic = idx >> 6, tap = idx & 63;
    float s = 0.0f;
    for (int c = 0; c < 128; ++c) s += dw3[(ic * 128 + c) * 64 + tap] * wo[c];
    dwe[idx] = s;
    if (idx == 0) {
        float bb = bo[0];
        for (int c = 0; c < 128; ++c) bb += wo[c] * db3[c];
        *beP = bb;
    }
}

__global__ void zero_kernel(float* __restrict__ la, float* __restrict__ zpage)
{
    zpage[threadIdx.x] = 0.0f;          // 256 floats = 1 KB zero page
    if (threadIdx.x == 0) la[0] = 0.0f;
}

// One batch VQ. h3 channels-last fp32 [spat][256]; q out channels-last bf16 hi/lo.
__global__ __launch_bounds__(256)
void vq_kernel(const float* __restrict__ h3, const float* __restrict__ emb,
               const float* __restrict__ eSq, unsigned short* __restrict__ qx,
               float* __restrict__ lossAcc)
{
    __shared__ float sDist[4][64];
    __shared__ int   sIdx[4][64];
    const int t = threadIdx.x;
    const int vec = blockIdx.x * 64 + (t & 63);
    const int kq = t >> 6;
    const int cg = vec & 3;
    const int spat = vec >> 2;
    const int base = spat * 256 + cg * 64;

    float v[64];
    #pragma unroll
    for (int e4 = 0; e4 < 16; ++e4) {
        float4 vv = *(const float4*)&h3[base + e4 * 4];
        v[e4 * 4]     = vv.x;
        v[e4 * 4 + 1] = vv.y;
        v[e4 * 4 + 2] = vv.z;
        v[e4 * 4 + 3] = vv.w;
    }

    float fSq = 0.0f;
    #pragma unroll
    for (int e = 0; e < 64; ++e) fSq += v[e] * v[e];

    float best = 1e30f; int bidx = 0;
    const int k0 = __builtin_amdgcn_readfirstlane(kq) * 128;
    for (int kk = 0; kk < 128; ++kk) {
        const int k = k0 + kk;
        const float* er = emb + k * 64;
        float d0 = 0, d1 = 0, d2 = 0, d3 = 0;
        #pragma unroll
        for (int e = 0; e < 64; e += 4) {
            d0 += v[e]     * er[e];
            d1 += v[e + 1] * er[e + 1];
            d2 += v[e + 2] * er[e + 2];
            d3 += v[e + 3] * er[e + 3];
        }
        const float s1 = fSq + eSq[k];
        const float dist = s1 - 2.0f * ((d0 + d1) + (d2 + d3));
        if (dist < best) { best = dist; bidx = k; }
    }
    sDist[kq][t & 63] = best;
    sIdx[kq][t & 63]  = bidx;
    __syncthreads();
    if (t < 64) {
        float bd = sDist[0][t]; int bi = sIdx[0][t];
        #pragma unroll
        for (int j = 1; j < 4; ++j) {
            float d = sDist[j][t]; int i2 = sIdx[j][t];
            if (d < bd || (d == bd && i2 < bi)) { bd = d; bi = i2; }
        }
        const float* er = emb + bi * 64;
        float ls = 0.0f;
        #pragma unroll
        for (int e = 0; e < 64; ++e) {
            float qe = er[e];
            int ic = cg * 64 + e;
            unsigned short hh, ll;
            bf16split(qe, hh, ll);
            size_t qi = ((size_t)spat * 32 + (ic >> 3)) * 16 + (ic & 7);
            qx[qi]     = hh;
            qx[qi + 8] = ll;
            float df = qe - v[e];
            ls += df * df;
        }
        #pragma unroll
        for (int off = 32; off > 0; off >>= 1) ls += __shfl_down(ls, off);
        if (t == 0) atomicAdd(lossAcc, ls);
    }
}

__global__ void loss_final(const float* __restrict__ lossAcc, float* __restrict__ out)
{
    out[0] = 1.25f * lossAcc[0] / 2097152.0f;
}

// ---------------------------------------------------------------------------
extern "C" void kernel_launch(void* const* d_in, const int* in_sizes, int n_in,
                              void* d_out, int out_size, void* d_ws, size_t ws_size,
                              hipStream_t stream)
{
    (void)in_sizes; (void)n_in; (void)out_size; (void)ws_size;
    const float* x   = (const float*)d_in[0];
    const float* w1  = (const float*)d_in[1];
    const float* b1  = (const float*)d_in[2];
    const float* w2  = (const float*)d_in[3];
    const float* b2  = (const float*)d_in[4];
    const float* w3  = (const float*)d_in[5];
    const float* b3  = (const float*)d_in[6];
    const float* dw1 = (const float*)d_in[7];
    const float* db1 = (const float*)d_in[8];
    const float* dw2 = (const float*)d_in[9];
    const float* db2 = (const float*)d_in[10];
    const float* dw3 = (const float*)d_in[11];
    const float* db3 = (const float*)d_in[12];
    const float* wo  = (const float*)d_in[13];
    const float* bo  = (const float*)d_in[14];
    const float* emb = (const float*)d_in[15];

    // Workspace (floats), ~227 MB peak (same as R6-passing layout).
    float* ws   = (float*)d_ws;
    float* A    = ws;                          // 33,554,432  h1x (bf16 cl) / conv3 partials / r2 fp32
    float* Bb   = A + 33554432;                //  8,388,608  h2x (bf16 cl) / r1x (bf16 cl)
    float* C    = Bb + 8388608;                //  1,048,576  h3 (fp32 cl)
    float* Dq   = C + 1048576;                 //  1,048,576  qx (bf16 cl)
    float* wT1  = Dq + 1048576;                //      8,192  conv1 fp32
    float* Wc2f = wT1 + 8192;                  //  2,097,152  conv2 mfma weights
    float* Wc3f = Wc2f + 2097152;              //  4,194,304  conv3 mfma weights
    float* Wm1f = Wc3f + 4194304;              //  4,194,304  deconv1 mfma weights
    float* Wm2f = Wm1f + 4194304;              //  2,097,152  deconv2 mfma weights
    float* dwe  = Wm2f + 2097152;              //      8,192
    float* eSq  = dwe + 8192;                  //        512
    float* lossAcc = eSq + 512;                //          1
    float* beP  = lossAcc + 1;                 //          1
    float* zpage = lossAcc + 4;                //        256 (16B-aligned)

    unsigned short* h1x  = (unsigned short*)A;
    unsigned short* h2x  = (unsigned short*)Bb;
    unsigned short* qx   = (unsigned short*)Dq;
    unsigned short* r1x  = (unsigned short*)Bb;
    unsigned short* Wc2x = (unsigned short*)Wc2f;
    unsigned short* Wc3x = (unsigned short*)Wc3f;
    unsigned short* Wm1x = (unsigned short*)Wm1f;
    unsigned short* Wm2x = (unsigned short*)Wm2f;

    float* outLoss = (float*)d_out;
    float* outR    = (float*)d_out + 1;

    zero_kernel<<<dim3(1), 256, 0, stream>>>(lossAcc, zpage);

    // weight prep (once; reused by both batches)
    repack_w<1, 128, false><<<dim3(32), 256, 0, stream>>>(w1, wT1);
    repack_cmfma<128, 256><<<dim3(8192),  256, 0, stream>>>(w2, Wc2x);
    repack_cmfma<256, 256><<<dim3(16384), 256, 0, stream>>>(w3, Wc3x);
    repack_mfma<256, 256><<<dim3(16384), 256, 0, stream>>>(dw1, Wm1x);
    repack_mfma<256, 128><<<dim3(8192),  256, 0, stream>>>(dw2, Wm2x);
    fold_kernel<<<dim3(32), 256, 0, stream>>>(dw3, wo, db3, bo, dwe, beP);
    esq_kernel<<<dim3(2), 256, 0, stream>>>(emb, eSq);

    for (int b = 0; b < 2; ++b) {
        const float* xb = x + (size_t)b * 2097152;
        float* rb = outR + (size_t)b * 2097152;

        // conv1: fp32 scalar -> h1x (bf16 cl)
        conv_sw_cl<1, 128, 128, true, 1, 64><<<dim3(1024, 2), 256, 0, stream>>>(xb, wT1, b1, h1x);

        // conv2: MFMA, bias+relu -> h2x (bf16 cl)
        conv_mfma<128, 256, 64, false, true><<<dim3(256, 1, 2), 256, 0, stream>>>(h1x, Wc2x, b2, nullptr, h2x, zpage);

        // conv3: MFMA, tap-split 8 -> fp32 cl partials in A, then reduce+bias -> C
        conv_mfma<256, 256, 32, true, false><<<dim3(32, 8, 2), 256, 0, stream>>>(h2x, Wc3x, b3, A, nullptr, zpage);
        reduce8_bias_cl<<<dim3(1024), 256, 0, stream>>>(A, b3, C);

        // VQ -> qx (bf16 cl) + loss
        vq_kernel<<<dim3(256), 256, 0, stream>>>(C, emb, eSq, qx, lossAcc);

        // decoder (MFMA)
        deconv_mfma<256, 256, 16, true ><<<dim3(32, 8, 2),  256, 0, stream>>>(qx,  Wm1x, db1, nullptr, r1x, zpage);
        deconv_mfma<256, 128, 32, false><<<dim3(256, 8, 1), 256, 0, stream>>>(r1x, Wm2x, db2, A, nullptr, zpage);

        deconv_final_sw<<<dim3(128), 256, 0, stream>>>(A, dwe, beP, rb);
    }

    loss_final<<<dim3(1), 1, 0, stream>>>(lossAcc, outLoss);
}